// Round 14
// baseline (197.186 us; speedup 1.0000x reference)
//
#include <hip/hip_runtime.h>
#include <hip/hip_bf16.h>
#include <float.h>

#define NNODES 100000
#define NEDGES 25000
#define NINC   800000
#define NH     4

#define NBLK_N ((NNODES + 127) / 128)
#define NBLK_E ((NEDGES + 127) / 128)
#define NPROJ (NBLK_N + NBLK_E)
#define CSR_BLKS ((NINC + 255) / 256)
#define HIST_BLKS ((NINC + 255) / 256)
#define ASSIGN_BLKS ((NNODES + 255) / 256)

typedef short bf16x8 __attribute__((ext_vector_type(8)));
typedef float f32x4  __attribute__((ext_vector_type(4)));
typedef unsigned int u32x4 __attribute__((ext_vector_type(4)));

// bf16 <-> f32 helpers (RNE pack, shift unpack)
__device__ __forceinline__ float bf2f(unsigned int u16)
{
    union { unsigned int u; float f; } c;
    c.u = u16 << 16;
    return c.f;
}
__device__ __forceinline__ unsigned int f2bf(float f)
{
    union { float f; unsigned int u; } c;
    c.f = f;
    return (c.u + 0x7FFFu + ((c.u >> 16) & 1u)) >> 16;
}

// ---------------------------------------------------------------------------
// K0: prep — {edge CSR} + {node histogram (cnt pre-zeroed by memsetAsync)}
//          + {W -> W^T bf16 swizzled}, one dispatch, independent block roles.
__global__ void prep_kernel(const int* __restrict__ eidx, int* __restrict__ edge_start,
                            const int* __restrict__ nidx, int* __restrict__ cnt,
                            const float* __restrict__ Wn, const float* __restrict__ We,
                            ushort* __restrict__ WTn, ushort* __restrict__ WTe)
{
    if (blockIdx.x < CSR_BLKS) {
        const int i = blockIdx.x * 256 + threadIdx.x;
        if (i < NINC) {
            const int cur  = eidx[i];
            const int prev = (i == 0) ? -1 : eidx[i - 1];
            for (int e = prev + 1; e <= cur; ++e) edge_start[e] = i;
            if (i == NINC - 1)
                for (int e = cur + 1; e <= NEDGES; ++e) edge_start[e] = NINC;
        }
    } else if (blockIdx.x < CSR_BLKS + HIST_BLKS) {
        const int i = (blockIdx.x - CSR_BLKS) * 256 + threadIdx.x;
        if (i < NINC) atomicAdd(&cnt[nidx[i]], 1);
    } else {
        const int gid = (blockIdx.x - CSR_BLKS - HIST_BLKS) * 256 + threadIdx.x;
        const float* W = (gid < 2048) ? Wn : We;
        ushort* WT     = (gid < 2048) ? WTn : WTe;
        const int g  = gid & 2047;
        const int n  = g >> 4, kq = g & 15;
        unsigned int pk[8];
#pragma unroll
        for (int u = 0; u < 8; ++u)
            pk[u] = f2bf(W[(kq * 8 + u) * 128 + n]);
        uint4 v;
        v.x = pk[0] | (pk[1] << 16);
        v.y = pk[2] | (pk[3] << 16);
        v.z = pk[4] | (pk[5] << 16);
        v.w = pk[6] | (pk[7] << 16);
        *(uint4*)&WT[n * 128 + ((kq ^ (n & 7)) * 8)] = v;
    }
}

// ---------------------------------------------------------------------------
// K1: MFMA projection (both matrices; 128 rows / 512 threads / 8 waves per
// block, 64KB LDS -> 2 blocks/CU = 16 waves/CU) + assign blocks in front.
__global__ __launch_bounds__(512, 2) void proj_assign_kernel(
    const float* __restrict__ Xn, const float* __restrict__ Xe,
    const ushort* __restrict__ WTn, const ushort* __restrict__ WTe,
    const float* __restrict__ attn_l, const float* __restrict__ attn_r,
    ushort* __restrict__ featsn, ushort* __restrict__ featse,
    float* __restrict__ alphan, float* __restrict__ alphae,
    const int* __restrict__ cnt, int* __restrict__ node_start,
    int* __restrict__ cursor, int* __restrict__ gcursor)
{
    __shared__ uint4  sX[128 * 16];    // [row][slot] bf16x8 slots, swizzled; 32KB
    __shared__ ushort sWT[128 * 128];  // pre-swizzled copy of WT; 32KB
    const int tid  = threadIdx.x;

    if (blockIdx.x < ASSIGN_BLKS) {
        // wave-aggregated slot allocation (first 256 threads)
        if (tid < 256) {
            const int n    = blockIdx.x * 256 + tid;
            const int lane = tid & 63;
            const int c = (n < NNODES) ? cnt[n] : 0;
            int incl = c;
#pragma unroll
            for (int d = 1; d < 64; d <<= 1) {
                const int v = __shfl_up(incl, d);
                if (lane >= d) incl += v;
            }
            const int total = __shfl(incl, 63);
            int base = 0;
            if (lane == 63) base = atomicAdd(gcursor, total);
            base = __shfl(base, 63);
            const int excl = incl - c;
            if (n < NNODES) {
                node_start[n] = base + excl;
                cursor[n]     = base + excl;
            }
        }
        return;
    }

    const int pb = blockIdx.x - ASSIGN_BLKS;
    const bool is_node = pb < NBLK_N;
    const int  bid  = is_node ? pb : pb - NBLK_N;
    const int  nrows = is_node ? NNODES : NEDGES;
    const float*  X     = is_node ? Xn : Xe;
    const ushort* WT    = is_node ? WTn : WTe;
    const float*  attn  = is_node ? attn_l : attn_r;
    ushort* feats_bf    = is_node ? featsn : featse;
    float*  alphav      = is_node ? alphan : alphae;
    const int row0 = bid * 128;

    // stage X -> bf16 LDS (coalesced f32x4 NT reads; X streamed once)
#pragma unroll
    for (int it = 0; it < 4; ++it) {
        const int si = tid + 512 * it;         // 0..2047
        const int r = si >> 4, slot = si & 15;
        const int grow = row0 + r;
        f32x4 v0 = (f32x4)0.f, v1 = (f32x4)0.f;
        if (grow < nrows) {
            v0 = __builtin_nontemporal_load((const f32x4*)X + grow * 32 + slot * 2);
            v1 = __builtin_nontemporal_load((const f32x4*)X + grow * 32 + slot * 2 + 1);
        }
        uint4 p;
        p.x = f2bf(v0[0]) | (f2bf(v0[1]) << 16);
        p.y = f2bf(v0[2]) | (f2bf(v0[3]) << 16);
        p.z = f2bf(v1[0]) | (f2bf(v1[1]) << 16);
        p.w = f2bf(v1[2]) | (f2bf(v1[3]) << 16);
        sX[r * 16 + (slot ^ (r & 7))] = p;
    }
    // stage pre-swizzled W^T (clean coalesced uint4 copy, L2-hot)
    {
        const uint4* WT4 = (const uint4*)WT;
        uint4* sWT4 = (uint4*)sWT;
#pragma unroll
        for (int it = 0; it < 4; ++it) sWT4[tid + 512 * it] = WT4[tid + 512 * it];
    }
    __syncthreads();

    const int w = tid >> 6, lane = tid & 63;   // w in [0,8)
    const int m = lane & 15, kq = lane >> 4;
    f32x4 acc[8];
#pragma unroll
    for (int ct = 0; ct < 8; ++ct) acc[ct] = (f32x4)0.f;

    const int r = w * 16 + m;  // r&7 == m&7
#pragma unroll
    for (int ks = 0; ks < 4; ++ks) {
        const bf16x8 a = *(const bf16x8*)&sX[r * 16 + ((kq + 4 * ks) ^ (m & 7))];
#pragma unroll
        for (int ct = 0; ct < 8; ++ct) {
            const int n = ct * 16 + m;  // n&7 == m&7
            const bf16x8 b = *(const bf16x8*)&sWT[n * 128 + (((kq + 4 * ks) ^ (m & 7)) * 8)];
            acc[ct] = __builtin_amdgcn_mfma_f32_16x16x32_bf16(a, b, acc[ct], 0, 0, 0);
        }
    }

    // fused attention scores
    float att[8];
#pragma unroll
    for (int h = 0; h < 4; ++h) {
        att[2 * h]     = attn[h * 32 + m];
        att[2 * h + 1] = attn[h * 32 + 16 + m];
    }
#pragma unroll
    for (int reg = 0; reg < 4; ++reg) {
        const int grow = row0 + w * 16 + kq * 4 + reg;
        float p0 = acc[0][reg] * att[0] + acc[1][reg] * att[1];
        float p1 = acc[2][reg] * att[2] + acc[3][reg] * att[3];
        float p2 = acc[4][reg] * att[4] + acc[5][reg] * att[5];
        float p3 = acc[6][reg] * att[6] + acc[7][reg] * att[7];
#pragma unroll
        for (int d = 1; d < 16; d <<= 1) {
            p0 += __shfl_xor(p0, d);
            p1 += __shfl_xor(p1, d);
            p2 += __shfl_xor(p2, d);
            p3 += __shfl_xor(p3, d);
        }
        if (m == 0 && grow < nrows)
            ((float4*)alphav)[grow] = make_float4(p0, p1, p2, p3);
    }

    // epilogue: transpose through this wave's own 4KB region of sX.
    {
        ushort* sT = (ushort*)&sX[w * 16 * 16];
#pragma unroll
        for (int ct = 0; ct < 8; ++ct) {
#pragma unroll
            for (int reg = 0; reg < 4; ++reg) {
                const int row  = kq * 4 + reg;
                const int phys = (ct * 2 + (m >> 3)) ^ ((row >> 2) << 1);
                sT[row * 128 + phys * 8 + (m & 7)] = (ushort)f2bf(acc[ct][reg]);
            }
        }
        asm volatile("s_waitcnt lgkmcnt(0)" ::: "memory");
#pragma unroll
        for (int p = 0; p < 4; ++p) {
            const int row  = p * 4 + (lane >> 4);
            const int sl   = lane & 15;
            const int phys = sl ^ ((row >> 2) << 1);
            const uint4 v  = *(const uint4*)&sT[row * 128 + phys * 8];
            const int grow = row0 + w * 16 + row;
            if (grow < nrows)
                *(uint4*)&feats_bf[grow * 128 + sl * 8] = v;
        }
    }
}

// ---------------------------------------------------------------------------
// K4: FUSED edge pipeline — one wave per edge. No-max softmax. Grouped n2e
// gather: 4 lane-groups x 16 lanes x 16B row slices, unroll-4 (16 j in flight).
__global__ __launch_bounds__(128) void fused_edge_kernel(
    const int* __restrict__ nidx, const int* __restrict__ estart,
    const float* __restrict__ alpha_l, const float* __restrict__ alpha_r,
    const unsigned int* __restrict__ node_feats_bf,
    const unsigned int* __restrict__ edge_feats_bf,
    int* __restrict__ cursor, u32x4* __restrict__ packG,
    unsigned int* __restrict__ edge_aggr_bf)
{
    __shared__ uint4 sInc[2][64];  // wave-private broadcast buffer
    const int e_id = (blockIdx.x * 128 + threadIdx.x) >> 6;
    const int lane = threadIdx.x & 63;
    const int w    = (threadIdx.x >> 6) & 1;
    if (e_id >= NEDGES) return;
    const int s = estart[e_id], t = estart[e_id + 1];
    if (s >= t) return;
    const int deg = t - s;
    const float4 ar = ((const float4*)alpha_r)[e_id];

    // ---- pass A: gather + exp + sum (chunks 0,1 cached in registers)
    int    nc0 = 0, nc1 = 0;
    float4 sc0 = make_float4(0.f, 0.f, 0.f, 0.f), sc1 = sc0;
    float s0 = 0.f, s1 = 0.f, s2 = 0.f, s3 = 0.f;
    if (s + lane < t) {
        nc0 = nidx[s + lane];
        const float4 al = ((const float4*)alpha_l)[nc0];
        sc0.x = __expf(al.x + ar.x); sc0.y = __expf(al.y + ar.y);
        sc0.z = __expf(al.z + ar.z); sc0.w = __expf(al.w + ar.w);
        s0 += sc0.x; s1 += sc0.y; s2 += sc0.z; s3 += sc0.w;
    }
    if (deg > 64 && s + 64 + lane < t) {
        nc1 = nidx[s + 64 + lane];
        const float4 al = ((const float4*)alpha_l)[nc1];
        sc1.x = __expf(al.x + ar.x); sc1.y = __expf(al.y + ar.y);
        sc1.z = __expf(al.z + ar.z); sc1.w = __expf(al.w + ar.w);
        s0 += sc1.x; s1 += sc1.y; s2 += sc1.z; s3 += sc1.w;
    }
    for (int c = 2; c * 64 < deg; ++c) {  // cold path (deg > 128)
        const int i = s + c * 64 + lane;
        if (i < t) {
            const float4 al = ((const float4*)alpha_l)[nidx[i]];
            s0 += __expf(al.x + ar.x); s1 += __expf(al.y + ar.y);
            s2 += __expf(al.z + ar.z); s3 += __expf(al.w + ar.w);
        }
    }
#pragma unroll
    for (int d = 1; d < 64; d <<= 1) {
        s0 += __shfl_xor(s0, d); s1 += __shfl_xor(s1, d);
        s2 += __shfl_xor(s2, d); s3 += __shfl_xor(s3, d);
    }
    const float i0 = 1.f / s0, i1 = 1.f / s1, i2 = 1.f / s2, i3 = 1.f / s3;

    // ---- pass B: publish (n, bf16-alpha) to LDS + packed scatter + grouped
    // n2e gather (unroll-4: 16 incidences, 4 row-gathers in flight).
    const int lg = lane >> 4, ll = lane & 15, hh = ll >> 2;
    float acc[8] = {0.f, 0.f, 0.f, 0.f, 0.f, 0.f, 0.f, 0.f};
    for (int c = 0; c * 64 < deg; ++c) {
        const int i = s + c * 64 + lane;
        int nn = 0;
        float4 a4 = make_float4(0.f, 0.f, 0.f, 0.f);
        if (c == 0) {
            nn = nc0;
            a4 = make_float4(sc0.x * i0, sc0.y * i1, sc0.z * i2, sc0.w * i3);
        } else if (c == 1) {
            nn = nc1;
            a4 = make_float4(sc1.x * i0, sc1.y * i1, sc1.z * i2, sc1.w * i3);
        } else if (i < t) {
            nn = nidx[i];
            const float4 al = ((const float4*)alpha_l)[nn];
            a4.x = __expf(al.x + ar.x) * i0; a4.y = __expf(al.y + ar.y) * i1;
            a4.z = __expf(al.z + ar.z) * i2; a4.w = __expf(al.w + ar.w) * i3;
        }
        const unsigned int a01 = f2bf(a4.x) | (f2bf(a4.y) << 16);
        const unsigned int a23 = f2bf(a4.z) | (f2bf(a4.w) << 16);
        if (i < t) {
            const int pos = atomicAdd(&cursor[nn], 1);
            u32x4 g4;
            g4[0] = (unsigned)e_id; g4[1] = a01; g4[2] = a23; g4[3] = 0u;
            packG[pos] = g4;
        }
        uint4 l4; l4.x = (unsigned)nn; l4.y = a01; l4.z = a23; l4.w = 0u;
        sInc[w][lane] = l4;
        asm volatile("s_waitcnt lgkmcnt(0)" ::: "memory");
        const int mj = min(64, deg - c * 64);
        int jj = 0;
        for (; jj + 16 <= mj; jj += 16) {
            uint4 P[4]; u32x4 V[4]; float Q[4];
#pragma unroll
            for (int u = 0; u < 4; ++u) P[u] = sInc[w][jj + 4 * u + lg];
#pragma unroll
            for (int u = 0; u < 4; ++u)
                V[u] = *(const u32x4*)(node_feats_bf + (size_t)P[u].x * 64 + ll * 4);
#pragma unroll
            for (int u = 0; u < 4; ++u) {
                const unsigned int pr = (hh & 2) ? P[u].z : P[u].y;
                Q[u] = bf2f((hh & 1) ? (pr >> 16) : (pr & 0xffffu));
            }
#pragma unroll
            for (int u = 0; u < 4; ++u)
#pragma unroll
                for (int k = 0; k < 4; ++k) {
                    acc[2 * k]     = fmaf(bf2f(V[u][k] & 0xffffu), Q[u], acc[2 * k]);
                    acc[2 * k + 1] = fmaf(bf2f(V[u][k] >> 16),     Q[u], acc[2 * k + 1]);
                }
        }
        for (; jj + 8 <= mj; jj += 8) {
            const uint4 p1 = sInc[w][jj + lg];
            const uint4 p2 = sInc[w][jj + 4 + lg];
            const u32x4 v1 = *(const u32x4*)(node_feats_bf + (size_t)p1.x * 64 + ll * 4);
            const u32x4 v2 = *(const u32x4*)(node_feats_bf + (size_t)p2.x * 64 + ll * 4);
            const unsigned int pr1 = (hh & 2) ? p1.z : p1.y;
            const unsigned int pr2 = (hh & 2) ? p2.z : p2.y;
            const float q1 = bf2f((hh & 1) ? (pr1 >> 16) : (pr1 & 0xffffu));
            const float q2 = bf2f((hh & 1) ? (pr2 >> 16) : (pr2 & 0xffffu));
#pragma unroll
            for (int k = 0; k < 4; ++k) {
                acc[2 * k]     = fmaf(bf2f(v1[k] & 0xffffu), q1, acc[2 * k]);
                acc[2 * k + 1] = fmaf(bf2f(v1[k] >> 16),     q1, acc[2 * k + 1]);
                acc[2 * k]     = fmaf(bf2f(v2[k] & 0xffffu), q2, acc[2 * k]);
                acc[2 * k + 1] = fmaf(bf2f(v2[k] >> 16),     q2, acc[2 * k + 1]);
            }
        }
        for (; jj < mj; jj += 4) {
            const int j = jj + lg;
            if (j < mj) {
                const uint4 p = sInc[w][j];
                const u32x4 v = *(const u32x4*)(node_feats_bf + (size_t)p.x * 64 + ll * 4);
                const unsigned int pr = (hh & 2) ? p.z : p.y;
                const float q = bf2f((hh & 1) ? (pr >> 16) : (pr & 0xffffu));
#pragma unroll
                for (int k = 0; k < 4; ++k) {
                    acc[2 * k]     = fmaf(bf2f(v[k] & 0xffffu), q, acc[2 * k]);
                    acc[2 * k + 1] = fmaf(bf2f(v[k] >> 16),     q, acc[2 * k + 1]);
                }
            }
        }
    }

    // butterfly-reduce across the 4 groups
#pragma unroll
    for (int k = 0; k < 8; ++k) {
        acc[k] += __shfl_xor(acc[k], 16);
        acc[k] += __shfl_xor(acc[k], 32);
    }
    if (lg == 0) {
        const u32x4 ef = *(const u32x4*)(edge_feats_bf + (size_t)e_id * 64 + ll * 4);
        u32x4 o;
#pragma unroll
        for (int k = 0; k < 4; ++k) {
            const float lo = acc[2 * k]     + bf2f(ef[k] & 0xffffu);
            const float hi = acc[2 * k + 1] + bf2f(ef[k] >> 16);
            o[k] = f2bf(lo) | (f2bf(hi) << 16);
        }
        *(u32x4*)(edge_aggr_bf + (size_t)e_id * 64 + ll * 4) = o;
    }
}

// ---------------------------------------------------------------------------
// K5: edge->node gather, 4-group x 16B-slice structure, butterfly epilogue.
__global__ __launch_bounds__(128) void e2n_gather_kernel(
    const u32x4* __restrict__ packG, const int* __restrict__ node_start,
    const int* __restrict__ cnt, const unsigned int* __restrict__ edge_aggr_bf,
    const float* __restrict__ bias, float* __restrict__ out)
{
    const int n    = (blockIdx.x * 128 + threadIdx.x) >> 6;
    const int lane = threadIdx.x & 63;
    if (n >= NNODES) return;
    const int s   = node_start[n];
    const int deg = cnt[n];
    const int lg = lane >> 4, ll = lane & 15, hh = ll >> 2;
    float acc[8] = {0.f, 0.f, 0.f, 0.f, 0.f, 0.f, 0.f, 0.f};
    int jj = 0;
    for (; jj + 8 <= deg; jj += 8) {
        const u32x4 p1 = packG[s + jj + lg];
        const u32x4 p2 = packG[s + jj + 4 + lg];
        const u32x4 v1 = *(const u32x4*)(edge_aggr_bf + (size_t)p1[0] * 64 + ll * 4);
        const u32x4 v2 = *(const u32x4*)(edge_aggr_bf + (size_t)p2[0] * 64 + ll * 4);
        const unsigned int pr1 = (hh & 2) ? p1[2] : p1[1];
        const unsigned int pr2 = (hh & 2) ? p2[2] : p2[1];
        const float q1 = bf2f((hh & 1) ? (pr1 >> 16) : (pr1 & 0xffffu));
        const float q2 = bf2f((hh & 1) ? (pr2 >> 16) : (pr2 & 0xffffu));
#pragma unroll
        for (int k = 0; k < 4; ++k) {
            acc[2 * k]     = fmaf(bf2f(v1[k] & 0xffffu), q1, acc[2 * k]);
            acc[2 * k + 1] = fmaf(bf2f(v1[k] >> 16),     q1, acc[2 * k + 1]);
            acc[2 * k]     = fmaf(bf2f(v2[k] & 0xffffu), q2, acc[2 * k]);
            acc[2 * k + 1] = fmaf(bf2f(v2[k] >> 16),     q2, acc[2 * k + 1]);
        }
    }
    for (; jj < deg; jj += 4) {
        const int j = jj + lg;
        if (j < deg) {
            const u32x4 p = packG[s + j];
            const u32x4 v = *(const u32x4*)(edge_aggr_bf + (size_t)p[0] * 64 + ll * 4);
            const unsigned int pr = (hh & 2) ? p[2] : p[1];
            const float q = bf2f((hh & 1) ? (pr >> 16) : (pr & 0xffffu));
#pragma unroll
            for (int k = 0; k < 4; ++k) {
                acc[2 * k]     = fmaf(bf2f(v[k] & 0xffffu), q, acc[2 * k]);
                acc[2 * k + 1] = fmaf(bf2f(v[k] >> 16),     q, acc[2 * k + 1]);
            }
        }
    }
#pragma unroll
    for (int k = 0; k < 8; ++k) {
        acc[k] += __shfl_xor(acc[k], 16);
        acc[k] += __shfl_xor(acc[k], 32);
    }
    if (lg < 2) {
        f32x4 o;
#pragma unroll
        for (int k = 0; k < 4; ++k)
            o[k] = acc[4 * lg + k] + bias[8 * ll + 4 * lg + k];
        __builtin_nontemporal_store(o, (f32x4*)(out + (size_t)n * 128 + ll * 8 + lg * 4));
    }
}

// ---------------------------------------------------------------------------
extern "C" void kernel_launch(void* const* d_in, const int* in_sizes, int n_in,
                              void* d_out, int out_size, void* d_ws, size_t ws_size,
                              hipStream_t stream)
{
    const float* x      = (const float*)d_in[0];
    const float* he     = (const float*)d_in[1];
    const int*   nidx   = (const int*)d_in[2];
    const int*   eidx   = (const int*)d_in[3];
    const float* Wn     = (const float*)d_in[4];
    const float* We     = (const float*)d_in[5];
    const float* attn_l = (const float*)d_in[6];
    const float* attn_r = (const float*)d_in[7];
    const float* bias   = (const float*)d_in[8];
    float* out = (float*)d_out;

    char* ws = (char*)d_ws;
    ushort* node_feats = (ushort*)ws;  ws += (size_t)NNODES * 128 * 2;
    ushort* edge_feats = (ushort*)ws;  ws += (size_t)NEDGES * 128 * 2;
    float* alpha_l     = (float*)ws;   ws += (size_t)NNODES * 4 * 4;
    float* alpha_r     = (float*)ws;   ws += (size_t)NEDGES * 4 * 4;
    unsigned int* edge_aggr = (unsigned int*)ws; ws += (size_t)NEDGES * 64 * 4;
    int*   edge_start  = (int*)ws;     ws += (size_t)(NEDGES + 4) * 4;
    int*   cnt         = (int*)ws;     ws += (size_t)(NNODES + 4) * 4;  // +gcursor
    int*   node_start  = (int*)ws;     ws += (size_t)(NNODES + 4) * 4;
    int*   cursor      = (int*)ws;     ws += (size_t)NNODES * 4;
    u32x4* packG       = (u32x4*)ws;   ws += (size_t)NINC * 16;
    ushort* WTn        = (ushort*)ws;  ws += (size_t)128 * 128 * 2;
    ushort* WTe        = (ushort*)ws;  ws += (size_t)128 * 128 * 2;
    int*   gcursor     = cnt + NNODES;

    // zero cnt (+gcursor), then prep: CSR + histogram + W^T, one dispatch
    hipMemsetAsync(cnt, 0, (size_t)(NNODES + 1) * 4, stream);
    prep_kernel<<<CSR_BLKS + HIST_BLKS + 16, 256, 0, stream>>>(
        eidx, edge_start, nidx, cnt, Wn, We, WTn, WTe);
    // assign (front blocks) + projections (128-row blocks), one dispatch
    proj_assign_kernel<<<ASSIGN_BLKS + NPROJ, 512, 0, stream>>>(
        x, he, WTn, WTe, attn_l, attn_r, node_feats, edge_feats, alpha_l, alpha_r,
        cnt, node_start, cursor, gcursor);
    // fused: softmax (no-max) + packed alpha scatter + grouped n2e aggregation
    fused_edge_kernel<<<(NEDGES * 64 + 127) / 128, 128, 0, stream>>>(
        nidx, edge_start, alpha_l, alpha_r, (const unsigned int*)node_feats,
        (const unsigned int*)edge_feats, cursor, packG, edge_aggr);
    // edge->node gather (grouped)
    e2n_gather_kernel<<<(NNODES * 64 + 127) / 128, 128, 0, stream>>>(
        packG, node_start, cnt, edge_aggr, bias, out);
}

// Round 15
// 196.614 us; speedup vs baseline: 1.0029x; 1.0029x over previous
//
#include <hip/hip_runtime.h>
#include <hip/hip_bf16.h>
#include <float.h>

#define NNODES 100000
#define NEDGES 25000
#define NINC   800000
#define NH     4

#define NBLK_N ((NNODES + 63) / 64)
#define NBLK_E ((NEDGES + 63) / 64)
#define CSR_BLKS ((NINC + 255) / 256)
#define HIST_BLKS ((NINC + 255) / 256)
#define NPROJ (NBLK_N + NBLK_E)

typedef short bf16x8 __attribute__((ext_vector_type(8)));
typedef float f32x4  __attribute__((ext_vector_type(4)));
typedef unsigned int u32x4 __attribute__((ext_vector_type(4)));

// bf16 <-> f32 helpers (RNE pack, shift unpack)
__device__ __forceinline__ float bf2f(unsigned int u16)
{
    union { unsigned int u; float f; } c;
    c.u = u16 << 16;
    return c.f;
}
__device__ __forceinline__ unsigned int f2bf(float f)
{
    union { float f; unsigned int u; } c;
    c.f = f;
    return (c.u + 0x7FFFu + ((c.u >> 16) & 1u)) >> 16;
}

// ---------------------------------------------------------------------------
// K0: prep — fused {edge CSR + zero histogram} and {W -> W^T bf16 swizzled}.
__global__ void prep_kernel(const int* __restrict__ eidx, int* __restrict__ edge_start,
                            int* __restrict__ cnt,
                            const float* __restrict__ Wn, const float* __restrict__ We,
                            ushort* __restrict__ WTn, ushort* __restrict__ WTe)
{
    if (blockIdx.x < CSR_BLKS) {
        const int i = blockIdx.x * 256 + threadIdx.x;
        if (i < NINC) {
            const int cur  = eidx[i];
            const int prev = (i == 0) ? -1 : eidx[i - 1];
            for (int e = prev + 1; e <= cur; ++e) edge_start[e] = i;
            if (i == NINC - 1)
                for (int e = cur + 1; e <= NEDGES; ++e) edge_start[e] = NINC;
        }
        if (i <= NNODES) cnt[i] = 0;  // includes gcursor at cnt[NNODES]
    } else {
        const int gid = (blockIdx.x - CSR_BLKS) * 256 + threadIdx.x;  // 0..4095
        const float* W = (gid < 2048) ? Wn : We;
        ushort* WT     = (gid < 2048) ? WTn : WTe;
        const int g  = gid & 2047;
        const int n  = g >> 4, kq = g & 15;
        unsigned int pk[8];
#pragma unroll
        for (int u = 0; u < 8; ++u)
            pk[u] = f2bf(W[(kq * 8 + u) * 128 + n]);
        uint4 v;
        v.x = pk[0] | (pk[1] << 16);
        v.y = pk[2] | (pk[3] << 16);
        v.z = pk[4] | (pk[5] << 16);
        v.w = pk[6] | (pk[7] << 16);
        *(uint4*)&WT[n * 128 + ((kq ^ (n & 7)) * 8)] = v;
    }
}

// ---------------------------------------------------------------------------
// K1: MFMA projection (both matrices) + node-degree histogram, one dispatch.
// LDS-light: only the X tile (16KB) is staged; B-fragments are read straight
// from the 32KB L2-resident W^T table -> ~5 blocks/CU instead of 3.
__global__ __launch_bounds__(256, 5) void proj_hist_kernel(
    const float* __restrict__ Xn, const float* __restrict__ Xe,
    const ushort* __restrict__ WTn, const ushort* __restrict__ WTe,
    const float* __restrict__ attn_l, const float* __restrict__ attn_r,
    ushort* __restrict__ featsn, ushort* __restrict__ featse,
    float* __restrict__ alphan, float* __restrict__ alphae,
    const int* __restrict__ nidx, int* __restrict__ cnt)
{
    __shared__ uint4 sX[64 * 16];  // [row][slot] bf16x8 slots, swizzled; 16KB
    const int tid = threadIdx.x;

    if (blockIdx.x < HIST_BLKS) {
        const int i = blockIdx.x * 256 + tid;
        if (i < NINC) atomicAdd(&cnt[nidx[i]], 1);
        return;
    }

    const int pb = blockIdx.x - HIST_BLKS;
    const bool is_node = pb < NBLK_N;
    const int  bid  = is_node ? pb : pb - NBLK_N;
    const int  nrows = is_node ? NNODES : NEDGES;
    const float*  X     = is_node ? Xn : Xe;
    const ushort* WT    = is_node ? WTn : WTe;
    const float*  attn  = is_node ? attn_l : attn_r;
    ushort* feats_bf    = is_node ? featsn : featse;
    float*  alphav      = is_node ? alphan : alphae;
    const int row0 = bid * 64;

    // stage X -> bf16 LDS (coalesced f32x4 NT reads; X streamed once)
#pragma unroll
    for (int it = 0; it < 4; ++it) {
        const int si = tid + 256 * it;         // 0..1023
        const int r = si >> 4, slot = si & 15;
        const int grow = row0 + r;
        f32x4 v0 = (f32x4)0.f, v1 = (f32x4)0.f;
        if (grow < nrows) {
            v0 = __builtin_nontemporal_load((const f32x4*)X + grow * 32 + slot * 2);
            v1 = __builtin_nontemporal_load((const f32x4*)X + grow * 32 + slot * 2 + 1);
        }
        uint4 p;
        p.x = f2bf(v0[0]) | (f2bf(v0[1]) << 16);
        p.y = f2bf(v0[2]) | (f2bf(v0[3]) << 16);
        p.z = f2bf(v1[0]) | (f2bf(v1[1]) << 16);
        p.w = f2bf(v1[2]) | (f2bf(v1[3]) << 16);
        sX[r * 16 + (slot ^ (r & 7))] = p;
    }
    __syncthreads();

    const int w = tid >> 6, lane = tid & 63;
    const int m = lane & 15, kq = lane >> 4;
    f32x4 acc[8];
#pragma unroll
    for (int ct = 0; ct < 8; ++ct) acc[ct] = (f32x4)0.f;

    const int r = w * 16 + m;  // r&7 == m&7
#pragma unroll
    for (int ks = 0; ks < 4; ++ks) {
        const int sl = ((kq + 4 * ks) ^ (m & 7));
        const bf16x8 a = *(const bf16x8*)&sX[r * 16 + sl];
        bf16x8 b[8];
#pragma unroll
        for (int ct = 0; ct < 8; ++ct)
            b[ct] = *(const bf16x8*)&WT[(ct * 16 + m) * 128 + sl * 8];
#pragma unroll
        for (int ct = 0; ct < 8; ++ct)
            acc[ct] = __builtin_amdgcn_mfma_f32_16x16x32_bf16(a, b[ct], acc[ct], 0, 0, 0);
    }

    // fused attention scores
    float att[8];
#pragma unroll
    for (int h = 0; h < 4; ++h) {
        att[2 * h]     = attn[h * 32 + m];
        att[2 * h + 1] = attn[h * 32 + 16 + m];
    }
#pragma unroll
    for (int reg = 0; reg < 4; ++reg) {
        const int grow = row0 + w * 16 + kq * 4 + reg;
        float p0 = acc[0][reg] * att[0] + acc[1][reg] * att[1];
        float p1 = acc[2][reg] * att[2] + acc[3][reg] * att[3];
        float p2 = acc[4][reg] * att[4] + acc[5][reg] * att[5];
        float p3 = acc[6][reg] * att[6] + acc[7][reg] * att[7];
#pragma unroll
        for (int d = 1; d < 16; d <<= 1) {
            p0 += __shfl_xor(p0, d);
            p1 += __shfl_xor(p1, d);
            p2 += __shfl_xor(p2, d);
            p3 += __shfl_xor(p3, d);
        }
        if (m == 0 && grow < nrows)
            ((float4*)alphav)[grow] = make_float4(p0, p1, p2, p3);
    }

    // epilogue: transpose through this wave's own 4KB region of sX.
    {
        ushort* sT = (ushort*)&sX[w * 16 * 16];
#pragma unroll
        for (int ct = 0; ct < 8; ++ct) {
#pragma unroll
            for (int reg = 0; reg < 4; ++reg) {
                const int row  = kq * 4 + reg;
                const int phys = (ct * 2 + (m >> 3)) ^ ((row >> 2) << 1);
                sT[row * 128 + phys * 8 + (m & 7)] = (ushort)f2bf(acc[ct][reg]);
            }
        }
        asm volatile("s_waitcnt lgkmcnt(0)" ::: "memory");
#pragma unroll
        for (int p = 0; p < 4; ++p) {
            const int row  = p * 4 + (lane >> 4);
            const int sl   = lane & 15;
            const int phys = sl ^ ((row >> 2) << 1);
            const uint4 v  = *(const uint4*)&sT[row * 128 + phys * 8];
            const int grow = row0 + w * 16 + row;
            if (grow < nrows)
                *(uint4*)&feats_bf[grow * 128 + sl * 8] = v;
        }
    }
}

// ---------------------------------------------------------------------------
__global__ __launch_bounds__(256) void assign_kernel(
    const int* __restrict__ cnt, int* __restrict__ node_start,
    int* __restrict__ cursor, int* __restrict__ gcursor)
{
    const int n    = blockIdx.x * 256 + threadIdx.x;
    const int lane = threadIdx.x & 63;
    const int c = (n < NNODES) ? cnt[n] : 0;
    int incl = c;
#pragma unroll
    for (int d = 1; d < 64; d <<= 1) {
        const int v = __shfl_up(incl, d);
        if (lane >= d) incl += v;
    }
    const int total = __shfl(incl, 63);
    int base = 0;
    if (lane == 63) base = atomicAdd(gcursor, total);
    base = __shfl(base, 63);
    const int excl = incl - c;
    if (n < NNODES) {
        node_start[n] = base + excl;
        cursor[n]     = base + excl;
    }
}

// ---------------------------------------------------------------------------
// K4: FUSED edge pipeline — one wave per edge. No-max softmax. Grouped n2e
// gather: 4 lane-groups x 16 lanes x 16B row slices, unroll-4 (16 j in flight).
__global__ __launch_bounds__(128) void fused_edge_kernel(
    const int* __restrict__ nidx, const int* __restrict__ estart,
    const float* __restrict__ alpha_l, const float* __restrict__ alpha_r,
    const unsigned int* __restrict__ node_feats_bf,
    const unsigned int* __restrict__ edge_feats_bf,
    int* __restrict__ cursor, u32x4* __restrict__ packG,
    unsigned int* __restrict__ edge_aggr_bf)
{
    __shared__ uint4 sInc[2][64];  // wave-private broadcast buffer
    const int e_id = (blockIdx.x * 128 + threadIdx.x) >> 6;
    const int lane = threadIdx.x & 63;
    const int w    = (threadIdx.x >> 6) & 1;
    if (e_id >= NEDGES) return;
    const int s = estart[e_id], t = estart[e_id + 1];
    if (s >= t) return;
    const int deg = t - s;
    const float4 ar = ((const float4*)alpha_r)[e_id];

    // ---- pass A: gather + exp + sum (chunks 0,1 cached in registers)
    int    nc0 = 0, nc1 = 0;
    float4 sc0 = make_float4(0.f, 0.f, 0.f, 0.f), sc1 = sc0;
    float s0 = 0.f, s1 = 0.f, s2 = 0.f, s3 = 0.f;
    if (s + lane < t) {
        nc0 = nidx[s + lane];
        const float4 al = ((const float4*)alpha_l)[nc0];
        sc0.x = __expf(al.x + ar.x); sc0.y = __expf(al.y + ar.y);
        sc0.z = __expf(al.z + ar.z); sc0.w = __expf(al.w + ar.w);
        s0 += sc0.x; s1 += sc0.y; s2 += sc0.z; s3 += sc0.w;
    }
    if (deg > 64 && s + 64 + lane < t) {
        nc1 = nidx[s + 64 + lane];
        const float4 al = ((const float4*)alpha_l)[nc1];
        sc1.x = __expf(al.x + ar.x); sc1.y = __expf(al.y + ar.y);
        sc1.z = __expf(al.z + ar.z); sc1.w = __expf(al.w + ar.w);
        s0 += sc1.x; s1 += sc1.y; s2 += sc1.z; s3 += sc1.w;
    }
    for (int c = 2; c * 64 < deg; ++c) {  // cold path (deg > 128)
        const int i = s + c * 64 + lane;
        if (i < t) {
            const float4 al = ((const float4*)alpha_l)[nidx[i]];
            s0 += __expf(al.x + ar.x); s1 += __expf(al.y + ar.y);
            s2 += __expf(al.z + ar.z); s3 += __expf(al.w + ar.w);
        }
    }
#pragma unroll
    for (int d = 1; d < 64; d <<= 1) {
        s0 += __shfl_xor(s0, d); s1 += __shfl_xor(s1, d);
        s2 += __shfl_xor(s2, d); s3 += __shfl_xor(s3, d);
    }
    const float i0 = 1.f / s0, i1 = 1.f / s1, i2 = 1.f / s2, i3 = 1.f / s3;

    // ---- pass B: publish (n, bf16-alpha) to LDS + packed scatter + grouped
    // n2e gather (unroll-4: 16 incidences, 4 row-gathers in flight).
    const int lg = lane >> 4, ll = lane & 15, hh = ll >> 2;
    float acc[8] = {0.f, 0.f, 0.f, 0.f, 0.f, 0.f, 0.f, 0.f};
    for (int c = 0; c * 64 < deg; ++c) {
        const int i = s + c * 64 + lane;
        int nn = 0;
        float4 a4 = make_float4(0.f, 0.f, 0.f, 0.f);
        if (c == 0) {
            nn = nc0;
            a4 = make_float4(sc0.x * i0, sc0.y * i1, sc0.z * i2, sc0.w * i3);
        } else if (c == 1) {
            nn = nc1;
            a4 = make_float4(sc1.x * i0, sc1.y * i1, sc1.z * i2, sc1.w * i3);
        } else if (i < t) {
            nn = nidx[i];
            const float4 al = ((const float4*)alpha_l)[nn];
            a4.x = __expf(al.x + ar.x) * i0; a4.y = __expf(al.y + ar.y) * i1;
            a4.z = __expf(al.z + ar.z) * i2; a4.w = __expf(al.w + ar.w) * i3;
        }
        const unsigned int a01 = f2bf(a4.x) | (f2bf(a4.y) << 16);
        const unsigned int a23 = f2bf(a4.z) | (f2bf(a4.w) << 16);
        if (i < t) {
            const int pos = atomicAdd(&cursor[nn], 1);
            u32x4 g4;
            g4[0] = (unsigned)e_id; g4[1] = a01; g4[2] = a23; g4[3] = 0u;
            packG[pos] = g4;
        }
        uint4 l4; l4.x = (unsigned)nn; l4.y = a01; l4.z = a23; l4.w = 0u;
        sInc[w][lane] = l4;
        asm volatile("s_waitcnt lgkmcnt(0)" ::: "memory");
        const int mj = min(64, deg - c * 64);
        int jj = 0;
        for (; jj + 16 <= mj; jj += 16) {
            uint4 P[4]; u32x4 V[4]; float Q[4];
#pragma unroll
            for (int u = 0; u < 4; ++u) P[u] = sInc[w][jj + 4 * u + lg];
#pragma unroll
            for (int u = 0; u < 4; ++u)
                V[u] = *(const u32x4*)(node_feats_bf + (size_t)P[u].x * 64 + ll * 4);
#pragma unroll
            for (int u = 0; u < 4; ++u) {
                const unsigned int pr = (hh & 2) ? P[u].z : P[u].y;
                Q[u] = bf2f((hh & 1) ? (pr >> 16) : (pr & 0xffffu));
            }
#pragma unroll
            for (int u = 0; u < 4; ++u)
#pragma unroll
                for (int k = 0; k < 4; ++k) {
                    acc[2 * k]     = fmaf(bf2f(V[u][k] & 0xffffu), Q[u], acc[2 * k]);
                    acc[2 * k + 1] = fmaf(bf2f(V[u][k] >> 16),     Q[u], acc[2 * k + 1]);
                }
        }
        for (; jj + 8 <= mj; jj += 8) {
            const uint4 p1 = sInc[w][jj + lg];
            const uint4 p2 = sInc[w][jj + 4 + lg];
            const u32x4 v1 = *(const u32x4*)(node_feats_bf + (size_t)p1.x * 64 + ll * 4);
            const u32x4 v2 = *(const u32x4*)(node_feats_bf + (size_t)p2.x * 64 + ll * 4);
            const unsigned int pr1 = (hh & 2) ? p1.z : p1.y;
            const unsigned int pr2 = (hh & 2) ? p2.z : p2.y;
            const float q1 = bf2f((hh & 1) ? (pr1 >> 16) : (pr1 & 0xffffu));
            const float q2 = bf2f((hh & 1) ? (pr2 >> 16) : (pr2 & 0xffffu));
#pragma unroll
            for (int k = 0; k < 4; ++k) {
                acc[2 * k]     = fmaf(bf2f(v1[k] & 0xffffu), q1, acc[2 * k]);
                acc[2 * k + 1] = fmaf(bf2f(v1[k] >> 16),     q1, acc[2 * k + 1]);
                acc[2 * k]     = fmaf(bf2f(v2[k] & 0xffffu), q2, acc[2 * k]);
                acc[2 * k + 1] = fmaf(bf2f(v2[k] >> 16),     q2, acc[2 * k + 1]);
            }
        }
        for (; jj < mj; jj += 4) {
            const int j = jj + lg;
            if (j < mj) {
                const uint4 p = sInc[w][j];
                const u32x4 v = *(const u32x4*)(node_feats_bf + (size_t)p.x * 64 + ll * 4);
                const unsigned int pr = (hh & 2) ? p.z : p.y;
                const float q = bf2f((hh & 1) ? (pr >> 16) : (pr & 0xffffu));
#pragma unroll
                for (int k = 0; k < 4; ++k) {
                    acc[2 * k]     = fmaf(bf2f(v[k] & 0xffffu), q, acc[2 * k]);
                    acc[2 * k + 1] = fmaf(bf2f(v[k] >> 16),     q, acc[2 * k + 1]);
                }
            }
        }
    }

    // butterfly-reduce across the 4 groups
#pragma unroll
    for (int k = 0; k < 8; ++k) {
        acc[k] += __shfl_xor(acc[k], 16);
        acc[k] += __shfl_xor(acc[k], 32);
    }
    if (lg == 0) {
        const u32x4 ef = *(const u32x4*)(edge_feats_bf + (size_t)e_id * 64 + ll * 4);
        u32x4 o;
#pragma unroll
        for (int k = 0; k < 4; ++k) {
            const float lo = acc[2 * k]     + bf2f(ef[k] & 0xffffu);
            const float hi = acc[2 * k + 1] + bf2f(ef[k] >> 16);
            o[k] = f2bf(lo) | (f2bf(hi) << 16);
        }
        *(u32x4*)(edge_aggr_bf + (size_t)e_id * 64 + ll * 4) = o;
    }
}

// ---------------------------------------------------------------------------
// K5: edge->node gather, 4-group x 16B-slice structure, butterfly epilogue.
__global__ __launch_bounds__(128) void e2n_gather_kernel(
    const u32x4* __restrict__ packG, const int* __restrict__ node_start,
    const int* __restrict__ cnt, const unsigned int* __restrict__ edge_aggr_bf,
    const float* __restrict__ bias, float* __restrict__ out)
{
    const int n    = (blockIdx.x * 128 + threadIdx.x) >> 6;
    const int lane = threadIdx.x & 63;
    if (n >= NNODES) return;
    const int s   = node_start[n];
    const int deg = cnt[n];
    const int lg = lane >> 4, ll = lane & 15, hh = ll >> 2;
    float acc[8] = {0.f, 0.f, 0.f, 0.f, 0.f, 0.f, 0.f, 0.f};
    int jj = 0;
    for (; jj + 8 <= deg; jj += 8) {
        const u32x4 p1 = packG[s + jj + lg];
        const u32x4 p2 = packG[s + jj + 4 + lg];
        const u32x4 v1 = *(const u32x4*)(edge_aggr_bf + (size_t)p1[0] * 64 + ll * 4);
        const u32x4 v2 = *(const u32x4*)(edge_aggr_bf + (size_t)p2[0] * 64 + ll * 4);
        const unsigned int pr1 = (hh & 2) ? p1[2] : p1[1];
        const unsigned int pr2 = (hh & 2) ? p2[2] : p2[1];
        const float q1 = bf2f((hh & 1) ? (pr1 >> 16) : (pr1 & 0xffffu));
        const float q2 = bf2f((hh & 1) ? (pr2 >> 16) : (pr2 & 0xffffu));
#pragma unroll
        for (int k = 0; k < 4; ++k) {
            acc[2 * k]     = fmaf(bf2f(v1[k] & 0xffffu), q1, acc[2 * k]);
            acc[2 * k + 1] = fmaf(bf2f(v1[k] >> 16),     q1, acc[2 * k + 1]);
            acc[2 * k]     = fmaf(bf2f(v2[k] & 0xffffu), q2, acc[2 * k]);
            acc[2 * k + 1] = fmaf(bf2f(v2[k] >> 16),     q2, acc[2 * k + 1]);
        }
    }
    for (; jj < deg; jj += 4) {
        const int j = jj + lg;
        if (j < deg) {
            const u32x4 p = packG[s + j];
            const u32x4 v = *(const u32x4*)(edge_aggr_bf + (size_t)p[0] * 64 + ll * 4);
            const unsigned int pr = (hh & 2) ? p[2] : p[1];
            const float q = bf2f((hh & 1) ? (pr >> 16) : (pr & 0xffffu));
#pragma unroll
            for (int k = 0; k < 4; ++k) {
                acc[2 * k]     = fmaf(bf2f(v[k] & 0xffffu), q, acc[2 * k]);
                acc[2 * k + 1] = fmaf(bf2f(v[k] >> 16),     q, acc[2 * k + 1]);
            }
        }
    }
#pragma unroll
    for (int k = 0; k < 8; ++k) {
        acc[k] += __shfl_xor(acc[k], 16);
        acc[k] += __shfl_xor(acc[k], 32);
    }
    if (lg < 2) {
        f32x4 o;
#pragma unroll
        for (int k = 0; k < 4; ++k)
            o[k] = acc[4 * lg + k] + bias[8 * ll + 4 * lg + k];
        __builtin_nontemporal_store(o, (f32x4*)(out + (size_t)n * 128 + ll * 8 + lg * 4));
    }
}

// ---------------------------------------------------------------------------
extern "C" void kernel_launch(void* const* d_in, const int* in_sizes, int n_in,
                              void* d_out, int out_size, void* d_ws, size_t ws_size,
                              hipStream_t stream)
{
    const float* x      = (const float*)d_in[0];
    const float* he     = (const float*)d_in[1];
    const int*   nidx   = (const int*)d_in[2];
    const int*   eidx   = (const int*)d_in[3];
    const float* Wn     = (const float*)d_in[4];
    const float* We     = (const float*)d_in[5];
    const float* attn_l = (const float*)d_in[6];
    const float* attn_r = (const float*)d_in[7];
    const float* bias   = (const float*)d_in[8];
    float* out = (float*)d_out;

    char* ws = (char*)d_ws;
    ushort* node_feats = (ushort*)ws;  ws += (size_t)NNODES * 128 * 2;
    ushort* edge_feats = (ushort*)ws;  ws += (size_t)NEDGES * 128 * 2;
    float* alpha_l     = (float*)ws;   ws += (size_t)NNODES * 4 * 4;
    float* alpha_r     = (float*)ws;   ws += (size_t)NEDGES * 4 * 4;
    unsigned int* edge_aggr = (unsigned int*)ws; ws += (size_t)NEDGES * 64 * 4;
    int*   edge_start  = (int*)ws;     ws += (size_t)(NEDGES + 4) * 4;
    int*   cnt         = (int*)ws;     ws += (size_t)(NNODES + 4) * 4;  // +gcursor
    int*   node_start  = (int*)ws;     ws += (size_t)(NNODES + 4) * 4;
    int*   cursor      = (int*)ws;     ws += (size_t)NNODES * 4;
    u32x4* packG       = (u32x4*)ws;   ws += (size_t)NINC * 16;
    ushort* WTn        = (ushort*)ws;  ws += (size_t)128 * 128 * 2;
    ushort* WTe        = (ushort*)ws;  ws += (size_t)128 * 128 * 2;
    int*   gcursor     = cnt + NNODES;

    // prep: edge CSR + zero histogram + W^T (one dispatch)
    prep_kernel<<<CSR_BLKS + 16, 256, 0, stream>>>(eidx, edge_start, cnt, Wn, We, WTn, WTe);
    // histogram (blocks first) + projections (one dispatch; independent work)
    proj_hist_kernel<<<HIST_BLKS + NPROJ, 256, 0, stream>>>(
        x, he, WTn, WTe, attn_l, attn_r, node_feats, edge_feats, alpha_l, alpha_r,
        nidx, cnt);
    assign_kernel<<<(NNODES + 255) / 256, 256, 0, stream>>>(cnt, node_start, cursor, gcursor);
    // fused: softmax (no-max) + packed alpha scatter + grouped n2e aggregation
    fused_edge_kernel<<<(NEDGES * 64 + 127) / 128, 128, 0, stream>>>(
        nidx, edge_start, alpha_l, alpha_r, (const unsigned int*)node_feats,
        (const unsigned int*)edge_feats, cursor, packG, edge_aggr);
    // edge->node gather (grouped)
    e2n_gather_kernel<<<(NNODES * 64 + 127) / 128, 128, 0, stream>>>(
        packG, node_start, cnt, edge_aggr, bias, out);
}

// Round 16
// 195.494 us; speedup vs baseline: 1.0087x; 1.0057x over previous
//
#include <hip/hip_runtime.h>
#include <hip/hip_bf16.h>
#include <float.h>

#define NNODES 100000
#define NEDGES 25000
#define NINC   800000
#define NH     4

#define NBLK_N ((NNODES + 63) / 64)
#define NBLK_E ((NEDGES + 63) / 64)
#define CSR_BLKS ((NINC + 255) / 256)
#define HIST_BLKS ((NINC + 255) / 256)
#define NPROJ (NBLK_N + NBLK_E)
#define XBFN_BLKS ((NNODES * 16 + 255) / 256)
#define XBFE_BLKS ((NEDGES * 16 + 255) / 256)

typedef short bf16x8 __attribute__((ext_vector_type(8)));
typedef float f32x4  __attribute__((ext_vector_type(4)));
typedef unsigned int u32x4 __attribute__((ext_vector_type(4)));

// bf16 <-> f32 helpers (RNE pack, shift unpack)
__device__ __forceinline__ float bf2f(unsigned int u16)
{
    union { unsigned int u; float f; } c;
    c.u = u16 << 16;
    return c.f;
}
__device__ __forceinline__ unsigned int f2bf(float f)
{
    union { float f; unsigned int u; } c;
    c.f = f;
    return (c.u + 0x7FFFu + ((c.u >> 16) & 1u)) >> 16;
}

// ---------------------------------------------------------------------------
// K0: prep — {edge CSR + zero hist} | {W^T bf16 swizzled} | {X,HE -> bf16}.
__global__ void prep_kernel(const int* __restrict__ eidx, int* __restrict__ edge_start,
                            int* __restrict__ cnt,
                            const float* __restrict__ Wn, const float* __restrict__ We,
                            ushort* __restrict__ WTn, ushort* __restrict__ WTe,
                            const float* __restrict__ x, const float* __restrict__ he,
                            ushort* __restrict__ xbf, ushort* __restrict__ hebf)
{
    const int tid = threadIdx.x;
    if (blockIdx.x < CSR_BLKS) {
        const int i = blockIdx.x * 256 + tid;
        if (i < NINC) {
            const int cur  = eidx[i];
            const int prev = (i == 0) ? -1 : eidx[i - 1];
            for (int e = prev + 1; e <= cur; ++e) edge_start[e] = i;
            if (i == NINC - 1)
                for (int e = cur + 1; e <= NEDGES; ++e) edge_start[e] = NINC;
        }
        if (i <= NNODES) cnt[i] = 0;  // includes gcursor at cnt[NNODES]
    } else if (blockIdx.x < CSR_BLKS + 16) {
        const int gid = (blockIdx.x - CSR_BLKS) * 256 + tid;  // 0..4095
        const float* W = (gid < 2048) ? Wn : We;
        ushort* WT     = (gid < 2048) ? WTn : WTe;
        const int g  = gid & 2047;
        const int n  = g >> 4, kq = g & 15;
        unsigned int pk[8];
#pragma unroll
        for (int u = 0; u < 8; ++u)
            pk[u] = f2bf(W[(kq * 8 + u) * 128 + n]);
        u32x4 v;
        v[0] = pk[0] | (pk[1] << 16);
        v[1] = pk[2] | (pk[3] << 16);
        v[2] = pk[4] | (pk[5] << 16);
        v[3] = pk[6] | (pk[7] << 16);
        *(u32x4*)&WT[n * 128 + ((kq ^ (n & 7)) * 8)] = v;
    } else {
        const int base = blockIdx.x - CSR_BLKS - 16;
        const float* X;
        ushort* XB;
        int idx, lim;
        if (base < XBFN_BLKS) {
            X = x; XB = xbf;
            idx = base * 256 + tid; lim = NNODES * 16;
        } else {
            X = he; XB = hebf;
            idx = (base - XBFN_BLKS) * 256 + tid; lim = NEDGES * 16;
        }
        if (idx < lim) {
            const f32x4 v0 = __builtin_nontemporal_load((const f32x4*)X + idx * 2);
            const f32x4 v1 = __builtin_nontemporal_load((const f32x4*)X + idx * 2 + 1);
            u32x4 p;
            p[0] = f2bf(v0[0]) | (f2bf(v0[1]) << 16);
            p[1] = f2bf(v0[2]) | (f2bf(v0[3]) << 16);
            p[2] = f2bf(v1[0]) | (f2bf(v1[1]) << 16);
            p[3] = f2bf(v1[2]) | (f2bf(v1[3]) << 16);
            ((u32x4*)XB)[idx] = p;
        }
    }
}

// ---------------------------------------------------------------------------
// K1: MFMA projection (both matrices) + node-degree histogram, one dispatch.
// A-fragments read directly from global bf16 X (16 lines/instr, 4 instrs/wave);
// B from 32KB LDS sWT; epilogue transpose reuses sWT after a barrier.
__global__ __launch_bounds__(256, 4) void proj_hist_kernel(
    const ushort* __restrict__ Xn, const ushort* __restrict__ Xe,
    const ushort* __restrict__ WTn, const ushort* __restrict__ WTe,
    const float* __restrict__ attn_l, const float* __restrict__ attn_r,
    ushort* __restrict__ featsn, ushort* __restrict__ featse,
    float* __restrict__ alphan, float* __restrict__ alphae,
    const int* __restrict__ nidx, int* __restrict__ cnt)
{
    __shared__ ushort sWT[128 * 128];  // 32KB; reused as transpose buffer
    const int tid = threadIdx.x;

    if (blockIdx.x < HIST_BLKS) {
        const int i = blockIdx.x * 256 + tid;
        if (i < NINC) atomicAdd(&cnt[nidx[i]], 1);
        return;
    }

    const int pb = blockIdx.x - HIST_BLKS;
    const bool is_node = pb < NBLK_N;
    const int  bid  = is_node ? pb : pb - NBLK_N;
    const int  nrows = is_node ? NNODES : NEDGES;
    const ushort* XB    = is_node ? Xn : Xe;
    const ushort* WT    = is_node ? WTn : WTe;
    const float*  attn  = is_node ? attn_l : attn_r;
    ushort* feats_bf    = is_node ? featsn : featse;
    float*  alphav      = is_node ? alphan : alphae;
    const int row0 = bid * 64;

    // stage pre-swizzled W^T (coalesced uint4 copy, L2-hot)
    {
        const u32x4* WT4 = (const u32x4*)WT;
        u32x4* sWT4 = (u32x4*)sWT;
#pragma unroll
        for (int it = 0; it < 8; ++it) sWT4[tid + 256 * it] = WT4[tid + 256 * it];
    }

    const int w = tid >> 6, lane = tid & 63;
    const int m = lane & 15, kq = lane >> 4;
    const int grow_a = row0 + w * 16 + m;

    // A-fragments straight from global bf16 X (prefetch all 4 K-steps)
    bf16x8 afr[4];
    if (grow_a < nrows) {
#pragma unroll
        for (int ks = 0; ks < 4; ++ks)
            afr[ks] = *(const bf16x8*)&XB[(size_t)grow_a * 128 + (kq + 4 * ks) * 8];
    } else {
#pragma unroll
        for (int ks = 0; ks < 4; ++ks) afr[ks] = (bf16x8)(short)0;
    }
    // attn weights (small, L2-hot)
    float att[8];
#pragma unroll
    for (int h = 0; h < 4; ++h) {
        att[2 * h]     = attn[h * 32 + m];
        att[2 * h + 1] = attn[h * 32 + 16 + m];
    }
    __syncthreads();

    f32x4 acc[8];
#pragma unroll
    for (int ct = 0; ct < 8; ++ct) acc[ct] = (f32x4)0.f;
#pragma unroll
    for (int ks = 0; ks < 4; ++ks) {
        const int sl = ((kq + 4 * ks) ^ (m & 7));
#pragma unroll
        for (int ct = 0; ct < 8; ++ct) {
            const bf16x8 b = *(const bf16x8*)&sWT[(ct * 16 + m) * 128 + sl * 8];
            acc[ct] = __builtin_amdgcn_mfma_f32_16x16x32_bf16(afr[ks], b, acc[ct], 0, 0, 0);
        }
    }

    // fused attention scores
#pragma unroll
    for (int reg = 0; reg < 4; ++reg) {
        const int grow = row0 + w * 16 + kq * 4 + reg;
        float p0 = acc[0][reg] * att[0] + acc[1][reg] * att[1];
        float p1 = acc[2][reg] * att[2] + acc[3][reg] * att[3];
        float p2 = acc[4][reg] * att[4] + acc[5][reg] * att[5];
        float p3 = acc[6][reg] * att[6] + acc[7][reg] * att[7];
#pragma unroll
        for (int d = 1; d < 16; d <<= 1) {
            p0 += __shfl_xor(p0, d);
            p1 += __shfl_xor(p1, d);
            p2 += __shfl_xor(p2, d);
            p3 += __shfl_xor(p3, d);
        }
        if (m == 0 && grow < nrows)
            ((float4*)alphav)[grow] = make_float4(p0, p1, p2, p3);
    }

    // epilogue: all waves done with sWT -> reuse it as transpose buffer
    __syncthreads();
    {
        ushort* sT = &sWT[w * 16 * 128];  // 4KB per wave
#pragma unroll
        for (int ct = 0; ct < 8; ++ct) {
#pragma unroll
            for (int reg = 0; reg < 4; ++reg) {
                const int row  = kq * 4 + reg;
                const int phys = (ct * 2 + (m >> 3)) ^ ((row >> 2) << 1);
                sT[row * 128 + phys * 8 + (m & 7)] = (ushort)f2bf(acc[ct][reg]);
            }
        }
        asm volatile("s_waitcnt lgkmcnt(0)" ::: "memory");
#pragma unroll
        for (int p = 0; p < 4; ++p) {
            const int row  = p * 4 + (lane >> 4);
            const int sl   = lane & 15;
            const int phys = sl ^ ((row >> 2) << 1);
            const uint4 v  = *(const uint4*)&sT[row * 128 + phys * 8];
            const int grow = row0 + w * 16 + row;
            if (grow < nrows)
                *(uint4*)&feats_bf[grow * 128 + sl * 8] = v;
        }
    }
}

// ---------------------------------------------------------------------------
__global__ __launch_bounds__(256) void assign_kernel(
    const int* __restrict__ cnt, int* __restrict__ node_start,
    int* __restrict__ cursor, int* __restrict__ gcursor)
{
    const int n    = blockIdx.x * 256 + threadIdx.x;
    const int lane = threadIdx.x & 63;
    const int c = (n < NNODES) ? cnt[n] : 0;
    int incl = c;
#pragma unroll
    for (int d = 1; d < 64; d <<= 1) {
        const int v = __shfl_up(incl, d);
        if (lane >= d) incl += v;
    }
    const int total = __shfl(incl, 63);
    int base = 0;
    if (lane == 63) base = atomicAdd(gcursor, total);
    base = __shfl(base, 63);
    const int excl = incl - c;
    if (n < NNODES) {
        node_start[n] = base + excl;
        cursor[n]     = base + excl;
    }
}

// ---------------------------------------------------------------------------
// K4: FUSED edge pipeline — one wave per edge. No-max softmax. Grouped n2e
// gather: 4 lane-groups x 16 lanes x 16B row slices, unroll-4 (16 j in flight).
__global__ __launch_bounds__(128) void fused_edge_kernel(
    const int* __restrict__ nidx, const int* __restrict__ estart,
    const float* __restrict__ alpha_l, const float* __restrict__ alpha_r,
    const unsigned int* __restrict__ node_feats_bf,
    const unsigned int* __restrict__ edge_feats_bf,
    int* __restrict__ cursor, u32x4* __restrict__ packG,
    unsigned int* __restrict__ edge_aggr_bf)
{
    __shared__ uint4 sInc[2][64];  // wave-private broadcast buffer
    const int e_id = (blockIdx.x * 128 + threadIdx.x) >> 6;
    const int lane = threadIdx.x & 63;
    const int w    = (threadIdx.x >> 6) & 1;
    if (e_id >= NEDGES) return;
    const int s = estart[e_id], t = estart[e_id + 1];
    if (s >= t) return;
    const int deg = t - s;
    const float4 ar = ((const float4*)alpha_r)[e_id];

    // ---- pass A: gather + exp + sum (chunks 0,1 cached in registers)
    int    nc0 = 0, nc1 = 0;
    float4 sc0 = make_float4(0.f, 0.f, 0.f, 0.f), sc1 = sc0;
    float s0 = 0.f, s1 = 0.f, s2 = 0.f, s3 = 0.f;
    if (s + lane < t) {
        nc0 = nidx[s + lane];
        const float4 al = ((const float4*)alpha_l)[nc0];
        sc0.x = __expf(al.x + ar.x); sc0.y = __expf(al.y + ar.y);
        sc0.z = __expf(al.z + ar.z); sc0.w = __expf(al.w + ar.w);
        s0 += sc0.x; s1 += sc0.y; s2 += sc0.z; s3 += sc0.w;
    }
    if (deg > 64 && s + 64 + lane < t) {
        nc1 = nidx[s + 64 + lane];
        const float4 al = ((const float4*)alpha_l)[nc1];
        sc1.x = __expf(al.x + ar.x); sc1.y = __expf(al.y + ar.y);
        sc1.z = __expf(al.z + ar.z); sc1.w = __expf(al.w + ar.w);
        s0 += sc1.x; s1 += sc1.y; s2 += sc1.z; s3 += sc1.w;
    }
    for (int c = 2; c * 64 < deg; ++c) {  // cold path (deg > 128)
        const int i = s + c * 64 + lane;
        if (i < t) {
            const float4 al = ((const float4*)alpha_l)[nidx[i]];
            s0 += __expf(al.x + ar.x); s1 += __expf(al.y + ar.y);
            s2 += __expf(al.z + ar.z); s3 += __expf(al.w + ar.w);
        }
    }
#pragma unroll
    for (int d = 1; d < 64; d <<= 1) {
        s0 += __shfl_xor(s0, d); s1 += __shfl_xor(s1, d);
        s2 += __shfl_xor(s2, d); s3 += __shfl_xor(s3, d);
    }
    const float i0 = 1.f / s0, i1 = 1.f / s1, i2 = 1.f / s2, i3 = 1.f / s3;

    // ---- pass B: publish (n, bf16-alpha) to LDS + packed scatter + grouped
    // n2e gather (unroll-4: 16 incidences, 4 row-gathers in flight).
    const int lg = lane >> 4, ll = lane & 15, hh = ll >> 2;
    float acc[8] = {0.f, 0.f, 0.f, 0.f, 0.f, 0.f, 0.f, 0.f};
    for (int c = 0; c * 64 < deg; ++c) {
        const int i = s + c * 64 + lane;
        int nn = 0;
        float4 a4 = make_float4(0.f, 0.f, 0.f, 0.f);
        if (c == 0) {
            nn = nc0;
            a4 = make_float4(sc0.x * i0, sc0.y * i1, sc0.z * i2, sc0.w * i3);
        } else if (c == 1) {
            nn = nc1;
            a4 = make_float4(sc1.x * i0, sc1.y * i1, sc1.z * i2, sc1.w * i3);
        } else if (i < t) {
            nn = nidx[i];
            const float4 al = ((const float4*)alpha_l)[nn];
            a4.x = __expf(al.x + ar.x) * i0; a4.y = __expf(al.y + ar.y) * i1;
            a4.z = __expf(al.z + ar.z) * i2; a4.w = __expf(al.w + ar.w) * i3;
        }
        const unsigned int a01 = f2bf(a4.x) | (f2bf(a4.y) << 16);
        const unsigned int a23 = f2bf(a4.z) | (f2bf(a4.w) << 16);
        if (i < t) {
            const int pos = atomicAdd(&cursor[nn], 1);
            u32x4 g4;
            g4[0] = (unsigned)e_id; g4[1] = a01; g4[2] = a23; g4[3] = 0u;
            packG[pos] = g4;
        }
        uint4 l4; l4.x = (unsigned)nn; l4.y = a01; l4.z = a23; l4.w = 0u;
        sInc[w][lane] = l4;
        asm volatile("s_waitcnt lgkmcnt(0)" ::: "memory");
        const int mj = min(64, deg - c * 64);
        int jj = 0;
        for (; jj + 16 <= mj; jj += 16) {
            uint4 P[4]; u32x4 V[4]; float Q[4];
#pragma unroll
            for (int u = 0; u < 4; ++u) P[u] = sInc[w][jj + 4 * u + lg];
#pragma unroll
            for (int u = 0; u < 4; ++u)
                V[u] = *(const u32x4*)(node_feats_bf + (size_t)P[u].x * 64 + ll * 4);
#pragma unroll
            for (int u = 0; u < 4; ++u) {
                const unsigned int pr = (hh & 2) ? P[u].z : P[u].y;
                Q[u] = bf2f((hh & 1) ? (pr >> 16) : (pr & 0xffffu));
            }
#pragma unroll
            for (int u = 0; u < 4; ++u)
#pragma unroll
                for (int k = 0; k < 4; ++k) {
                    acc[2 * k]     = fmaf(bf2f(V[u][k] & 0xffffu), Q[u], acc[2 * k]);
                    acc[2 * k + 1] = fmaf(bf2f(V[u][k] >> 16),     Q[u], acc[2 * k + 1]);
                }
        }
        for (; jj + 8 <= mj; jj += 8) {
            const uint4 p1 = sInc[w][jj + lg];
            const uint4 p2 = sInc[w][jj + 4 + lg];
            const u32x4 v1 = *(const u32x4*)(node_feats_bf + (size_t)p1.x * 64 + ll * 4);
            const u32x4 v2 = *(const u32x4*)(node_feats_bf + (size_t)p2.x * 64 + ll * 4);
            const unsigned int pr1 = (hh & 2) ? p1.z : p1.y;
            const unsigned int pr2 = (hh & 2) ? p2.z : p2.y;
            const float q1 = bf2f((hh & 1) ? (pr1 >> 16) : (pr1 & 0xffffu));
            const float q2 = bf2f((hh & 1) ? (pr2 >> 16) : (pr2 & 0xffffu));
#pragma unroll
            for (int k = 0; k < 4; ++k) {
                acc[2 * k]     = fmaf(bf2f(v1[k] & 0xffffu), q1, acc[2 * k]);
                acc[2 * k + 1] = fmaf(bf2f(v1[k] >> 16),     q1, acc[2 * k + 1]);
                acc[2 * k]     = fmaf(bf2f(v2[k] & 0xffffu), q2, acc[2 * k]);
                acc[2 * k + 1] = fmaf(bf2f(v2[k] >> 16),     q2, acc[2 * k + 1]);
            }
        }
        for (; jj < mj; jj += 4) {
            const int j = jj + lg;
            if (j < mj) {
                const uint4 p = sInc[w][j];
                const u32x4 v = *(const u32x4*)(node_feats_bf + (size_t)p.x * 64 + ll * 4);
                const unsigned int pr = (hh & 2) ? p.z : p.y;
                const float q = bf2f((hh & 1) ? (pr >> 16) : (pr & 0xffffu));
#pragma unroll
                for (int k = 0; k < 4; ++k) {
                    acc[2 * k]     = fmaf(bf2f(v[k] & 0xffffu), q, acc[2 * k]);
                    acc[2 * k + 1] = fmaf(bf2f(v[k] >> 16),     q, acc[2 * k + 1]);
                }
            }
        }
    }

    // butterfly-reduce across the 4 groups
#pragma unroll
    for (int k = 0; k < 8; ++k) {
        acc[k] += __shfl_xor(acc[k], 16);
        acc[k] += __shfl_xor(acc[k], 32);
    }
    if (lg == 0) {
        const u32x4 ef = *(const u32x4*)(edge_feats_bf + (size_t)e_id * 64 + ll * 4);
        u32x4 o;
#pragma unroll
        for (int k = 0; k < 4; ++k) {
            const float lo = acc[2 * k]     + bf2f(ef[k] & 0xffffu);
            const float hi = acc[2 * k + 1] + bf2f(ef[k] >> 16);
            o[k] = f2bf(lo) | (f2bf(hi) << 16);
        }
        *(u32x4*)(edge_aggr_bf + (size_t)e_id * 64 + ll * 4) = o;
    }
}

// ---------------------------------------------------------------------------
// K5: edge->node gather, 4-group x 16B-slice structure, butterfly epilogue.
__global__ __launch_bounds__(128) void e2n_gather_kernel(
    const u32x4* __restrict__ packG, const int* __restrict__ node_start,
    const int* __restrict__ cnt, const unsigned int* __restrict__ edge_aggr_bf,
    const float* __restrict__ bias, float* __restrict__ out)
{
    const int n    = (blockIdx.x * 128 + threadIdx.x) >> 6;
    const int lane = threadIdx.x & 63;
    if (n >= NNODES) return;
    const int s   = node_start[n];
    const int deg = cnt[n];
    const int lg = lane >> 4, ll = lane & 15, hh = ll >> 2;
    float acc[8] = {0.f, 0.f, 0.f, 0.f, 0.f, 0.f, 0.f, 0.f};
    int jj = 0;
    for (; jj + 8 <= deg; jj += 8) {
        const u32x4 p1 = packG[s + jj + lg];
        const u32x4 p2 = packG[s + jj + 4 + lg];
        const u32x4 v1 = *(const u32x4*)(edge_aggr_bf + (size_t)p1[0] * 64 + ll * 4);
        const u32x4 v2 = *(const u32x4*)(edge_aggr_bf + (size_t)p2[0] * 64 + ll * 4);
        const unsigned int pr1 = (hh & 2) ? p1[2] : p1[1];
        const unsigned int pr2 = (hh & 2) ? p2[2] : p2[1];
        const float q1 = bf2f((hh & 1) ? (pr1 >> 16) : (pr1 & 0xffffu));
        const float q2 = bf2f((hh & 1) ? (pr2 >> 16) : (pr2 & 0xffffu));
#pragma unroll
        for (int k = 0; k < 4; ++k) {
            acc[2 * k]     = fmaf(bf2f(v1[k] & 0xffffu), q1, acc[2 * k]);
            acc[2 * k + 1] = fmaf(bf2f(v1[k] >> 16),     q1, acc[2 * k + 1]);
            acc[2 * k]     = fmaf(bf2f(v2[k] & 0xffffu), q2, acc[2 * k]);
            acc[2 * k + 1] = fmaf(bf2f(v2[k] >> 16),     q2, acc[2 * k + 1]);
        }
    }
    for (; jj < deg; jj += 4) {
        const int j = jj + lg;
        if (j < deg) {
            const u32x4 p = packG[s + j];
            const u32x4 v = *(const u32x4*)(edge_aggr_bf + (size_t)p[0] * 64 + ll * 4);
            const unsigned int pr = (hh & 2) ? p[2] : p[1];
            const float q = bf2f((hh & 1) ? (pr >> 16) : (pr & 0xffffu));
#pragma unroll
            for (int k = 0; k < 4; ++k) {
                acc[2 * k]     = fmaf(bf2f(v[k] & 0xffffu), q, acc[2 * k]);
                acc[2 * k + 1] = fmaf(bf2f(v[k] >> 16),     q, acc[2 * k + 1]);
            }
        }
    }
#pragma unroll
    for (int k = 0; k < 8; ++k) {
        acc[k] += __shfl_xor(acc[k], 16);
        acc[k] += __shfl_xor(acc[k], 32);
    }
    if (lg < 2) {
        f32x4 o;
#pragma unroll
        for (int k = 0; k < 4; ++k)
            o[k] = acc[4 * lg + k] + bias[8 * ll + 4 * lg + k];
        __builtin_nontemporal_store(o, (f32x4*)(out + (size_t)n * 128 + ll * 8 + lg * 4));
    }
}

// ---------------------------------------------------------------------------
extern "C" void kernel_launch(void* const* d_in, const int* in_sizes, int n_in,
                              void* d_out, int out_size, void* d_ws, size_t ws_size,
                              hipStream_t stream)
{
    const float* x      = (const float*)d_in[0];
    const float* he     = (const float*)d_in[1];
    const int*   nidx   = (const int*)d_in[2];
    const int*   eidx   = (const int*)d_in[3];
    const float* Wn     = (const float*)d_in[4];
    const float* We     = (const float*)d_in[5];
    const float* attn_l = (const float*)d_in[6];
    const float* attn_r = (const float*)d_in[7];
    const float* bias   = (const float*)d_in[8];
    float* out = (float*)d_out;

    char* ws = (char*)d_ws;
    ushort* node_feats = (ushort*)ws;  ws += (size_t)NNODES * 128 * 2;
    ushort* edge_feats = (ushort*)ws;  ws += (size_t)NEDGES * 128 * 2;
    float* alpha_l     = (float*)ws;   ws += (size_t)NNODES * 4 * 4;
    float* alpha_r     = (float*)ws;   ws += (size_t)NEDGES * 4 * 4;
    unsigned int* edge_aggr = (unsigned int*)ws; ws += (size_t)NEDGES * 64 * 4;
    int*   edge_start  = (int*)ws;     ws += (size_t)(NEDGES + 4) * 4;
    int*   cnt         = (int*)ws;     ws += (size_t)(NNODES + 4) * 4;  // +gcursor
    int*   node_start  = (int*)ws;     ws += (size_t)(NNODES + 4) * 4;
    int*   cursor      = (int*)ws;     ws += (size_t)NNODES * 4;
    u32x4* packG       = (u32x4*)ws;   ws += (size_t)NINC * 16;
    ushort* WTn        = (ushort*)ws;  ws += (size_t)128 * 128 * 2;
    ushort* WTe        = (ushort*)ws;  ws += (size_t)128 * 128 * 2;
    ushort* xbf        = (ushort*)ws;  ws += (size_t)NNODES * 128 * 2;
    ushort* hebf       = (ushort*)ws;  ws += (size_t)NEDGES * 128 * 2;
    int*   gcursor     = cnt + NNODES;

    // prep: edge CSR + zero hist + W^T + X->bf16 (one dispatch)
    prep_kernel<<<CSR_BLKS + 16 + XBFN_BLKS + XBFE_BLKS, 256, 0, stream>>>(
        eidx, edge_start, cnt, Wn, We, WTn, WTe, x, he, xbf, hebf);
    // histogram (blocks first) + projections (one dispatch; independent work)
    proj_hist_kernel<<<HIST_BLKS + NPROJ, 256, 0, stream>>>(
        xbf, hebf, WTn, WTe, attn_l, attn_r, node_feats, edge_feats, alpha_l, alpha_r,
        nidx, cnt);
    assign_kernel<<<(NNODES + 255) / 256, 256, 0, stream>>>(cnt, node_start, cursor, gcursor);
    // fused: softmax (no-max) + packed alpha scatter + grouped n2e aggregation
    fused_edge_kernel<<<(NEDGES * 64 + 127) / 128, 128, 0, stream>>>(
        nidx, edge_start, alpha_l, alpha_r, (const unsigned int*)node_feats,
        (const unsigned int*)edge_feats, cursor, packG, edge_aggr);
    // edge->node gather (grouped)
    e2n_gather_kernel<<<(NNODES * 64 + 127) / 128, 128, 0, stream>>>(
        packG, node_start, cnt, edge_aggr, bias, out);
}

// Round 17
// 191.285 us; speedup vs baseline: 1.0308x; 1.0220x over previous
//
#include <hip/hip_runtime.h>
#include <hip/hip_bf16.h>
#include <float.h>

#define NNODES 100000
#define NEDGES 25000
#define NINC   800000
#define NH     4

#define NBLK_N ((NNODES + 63) / 64)
#define NBLK_E ((NEDGES + 63) / 64)
#define CSR_BLKS ((NINC + 255) / 256)
#define HIST_BLKS ((NINC + 255) / 256)
#define NPROJ (NBLK_N + NBLK_E)

typedef short bf16x8 __attribute__((ext_vector_type(8)));
typedef float f32x4  __attribute__((ext_vector_type(4)));
typedef unsigned int u32x4 __attribute__((ext_vector_type(4)));

// bf16 <-> f32 helpers (RNE pack, shift unpack)
__device__ __forceinline__ float bf2f(unsigned int u16)
{
    union { unsigned int u; float f; } c;
    c.u = u16 << 16;
    return c.f;
}
__device__ __forceinline__ unsigned int f2bf(float f)
{
    union { float f; unsigned int u; } c;
    c.f = f;
    return (c.u + 0x7FFFu + ((c.u >> 16) & 1u)) >> 16;
}

// ---------------------------------------------------------------------------
// K0: prep — fused {edge CSR + zero histogram} and {W -> W^T bf16 swizzled}.
__global__ void prep_kernel(const int* __restrict__ eidx, int* __restrict__ edge_start,
                            int* __restrict__ cnt,
                            const float* __restrict__ Wn, const float* __restrict__ We,
                            ushort* __restrict__ WTn, ushort* __restrict__ WTe)
{
    if (blockIdx.x < CSR_BLKS) {
        const int i = blockIdx.x * 256 + threadIdx.x;
        if (i < NINC) {
            const int cur  = eidx[i];
            const int prev = (i == 0) ? -1 : eidx[i - 1];
            for (int e = prev + 1; e <= cur; ++e) edge_start[e] = i;
            if (i == NINC - 1)
                for (int e = cur + 1; e <= NEDGES; ++e) edge_start[e] = NINC;
        }
        if (i <= NNODES) cnt[i] = 0;  // includes gcursor at cnt[NNODES]
    } else {
        const int gid = (blockIdx.x - CSR_BLKS) * 256 + threadIdx.x;  // 0..4095
        const float* W = (gid < 2048) ? Wn : We;
        ushort* WT     = (gid < 2048) ? WTn : WTe;
        const int g  = gid & 2047;
        const int n  = g >> 4, kq = g & 15;
        unsigned int pk[8];
#pragma unroll
        for (int u = 0; u < 8; ++u)
            pk[u] = f2bf(W[(kq * 8 + u) * 128 + n]);
        uint4 v;
        v.x = pk[0] | (pk[1] << 16);
        v.y = pk[2] | (pk[3] << 16);
        v.z = pk[4] | (pk[5] << 16);
        v.w = pk[6] | (pk[7] << 16);
        *(uint4*)&WT[n * 128 + ((kq ^ (n & 7)) * 8)] = v;
    }
}

// ---------------------------------------------------------------------------
// K1: MFMA projection (both matrices) + node-degree histogram, one dispatch.
// Blocks [0, HIST_BLKS): histogram. Blocks [HIST_BLKS, ...): projection.
__global__ __launch_bounds__(256, 3) void proj_hist_kernel(
    const float* __restrict__ Xn, const float* __restrict__ Xe,
    const ushort* __restrict__ WTn, const ushort* __restrict__ WTe,
    const float* __restrict__ attn_l, const float* __restrict__ attn_r,
    ushort* __restrict__ featsn, ushort* __restrict__ featse,
    float* __restrict__ alphan, float* __restrict__ alphae,
    const int* __restrict__ nidx, int* __restrict__ cnt)
{
    __shared__ uint4  sX[64 * 16];     // [row][slot] bf16x8 slots, swizzled
    __shared__ ushort sWT[128 * 128];  // pre-swizzled copy of WT
    const int tid  = threadIdx.x;

    if (blockIdx.x < HIST_BLKS) {
        const int i = blockIdx.x * 256 + tid;
        if (i < NINC) atomicAdd(&cnt[nidx[i]], 1);
        return;
    }

    const int pb = blockIdx.x - HIST_BLKS;
    const bool is_node = pb < NBLK_N;
    const int  bid  = is_node ? pb : pb - NBLK_N;
    const int  nrows = is_node ? NNODES : NEDGES;
    const float*  X     = is_node ? Xn : Xe;
    const ushort* WT    = is_node ? WTn : WTe;
    const float*  attn  = is_node ? attn_l : attn_r;
    ushort* feats_bf    = is_node ? featsn : featse;
    float*  alphav      = is_node ? alphan : alphae;
    const int row0 = bid * 64;

#pragma unroll
    for (int it = 0; it < 4; ++it) {
        const int si = tid + 256 * it;         // 0..1023
        const int r = si >> 4, slot = si & 15;
        const int grow = row0 + r;
        f32x4 v0 = (f32x4)0.f, v1 = (f32x4)0.f;
        if (grow < nrows) {
            v0 = __builtin_nontemporal_load((const f32x4*)X + grow * 32 + slot * 2);
            v1 = __builtin_nontemporal_load((const f32x4*)X + grow * 32 + slot * 2 + 1);
        }
        uint4 p;
        p.x = f2bf(v0[0]) | (f2bf(v0[1]) << 16);
        p.y = f2bf(v0[2]) | (f2bf(v0[3]) << 16);
        p.z = f2bf(v1[0]) | (f2bf(v1[1]) << 16);
        p.w = f2bf(v1[2]) | (f2bf(v1[3]) << 16);
        sX[r * 16 + (slot ^ (r & 7))] = p;
    }
    {
        const uint4* WT4 = (const uint4*)WT;
        uint4* sWT4 = (uint4*)sWT;
#pragma unroll
        for (int it = 0; it < 8; ++it) sWT4[tid + 256 * it] = WT4[tid + 256 * it];
    }
    __syncthreads();

    const int w = tid >> 6, lane = tid & 63;
    const int m = lane & 15, kq = lane >> 4;
    f32x4 acc[8];
#pragma unroll
    for (int ct = 0; ct < 8; ++ct) acc[ct] = (f32x4)0.f;

    const int r = w * 16 + m;  // r&7 == m&7
#pragma unroll
    for (int ks = 0; ks < 4; ++ks) {
        const bf16x8 a = *(const bf16x8*)&sX[r * 16 + ((kq + 4 * ks) ^ (m & 7))];
#pragma unroll
        for (int ct = 0; ct < 8; ++ct) {
            const int n = ct * 16 + m;  // n&7 == m&7
            const bf16x8 b = *(const bf16x8*)&sWT[n * 128 + (((kq + 4 * ks) ^ (m & 7)) * 8)];
            acc[ct] = __builtin_amdgcn_mfma_f32_16x16x32_bf16(a, b, acc[ct], 0, 0, 0);
        }
    }

    float att[8];
#pragma unroll
    for (int h = 0; h < 4; ++h) {
        att[2 * h]     = attn[h * 32 + m];
        att[2 * h + 1] = attn[h * 32 + 16 + m];
    }
#pragma unroll
    for (int reg = 0; reg < 4; ++reg) {
        const int grow = row0 + w * 16 + kq * 4 + reg;
        float p0 = acc[0][reg] * att[0] + acc[1][reg] * att[1];
        float p1 = acc[2][reg] * att[2] + acc[3][reg] * att[3];
        float p2 = acc[4][reg] * att[4] + acc[5][reg] * att[5];
        float p3 = acc[6][reg] * att[6] + acc[7][reg] * att[7];
#pragma unroll
        for (int d = 1; d < 16; d <<= 1) {
            p0 += __shfl_xor(p0, d);
            p1 += __shfl_xor(p1, d);
            p2 += __shfl_xor(p2, d);
            p3 += __shfl_xor(p3, d);
        }
        if (m == 0 && grow < nrows)
            ((float4*)alphav)[grow] = make_float4(p0, p1, p2, p3);
    }

    {
        ushort* sT = (ushort*)&sX[w * 16 * 16];
#pragma unroll
        for (int ct = 0; ct < 8; ++ct) {
#pragma unroll
            for (int reg = 0; reg < 4; ++reg) {
                const int row  = kq * 4 + reg;
                const int phys = (ct * 2 + (m >> 3)) ^ ((row >> 2) << 1);
                sT[row * 128 + phys * 8 + (m & 7)] = (ushort)f2bf(acc[ct][reg]);
            }
        }
        asm volatile("s_waitcnt lgkmcnt(0)" ::: "memory");
#pragma unroll
        for (int p = 0; p < 4; ++p) {
            const int row  = p * 4 + (lane >> 4);
            const int sl   = lane & 15;
            const int phys = sl ^ ((row >> 2) << 1);
            const uint4 v  = *(const uint4*)&sT[row * 128 + phys * 8];
            const int grow = row0 + w * 16 + row;
            if (grow < nrows)
                *(uint4*)&feats_bf[grow * 128 + sl * 8] = v;
        }
    }
}

// ---------------------------------------------------------------------------
__global__ __launch_bounds__(256) void assign_kernel(
    const int* __restrict__ cnt, int* __restrict__ node_start,
    int* __restrict__ cursor, int* __restrict__ gcursor)
{
    const int n    = blockIdx.x * 256 + threadIdx.x;
    const int lane = threadIdx.x & 63;
    const int c = (n < NNODES) ? cnt[n] : 0;
    int incl = c;
#pragma unroll
    for (int d = 1; d < 64; d <<= 1) {
        const int v = __shfl_up(incl, d);
        if (lane >= d) incl += v;
    }
    const int total = __shfl(incl, 63);
    int base = 0;
    if (lane == 63) base = atomicAdd(gcursor, total);
    base = __shfl(base, 63);
    const int excl = incl - c;
    if (n < NNODES) {
        node_start[n] = base + excl;
        cursor[n]     = base + excl;
    }
}

// ---------------------------------------------------------------------------
// K4: FUSED edge pipeline — one wave per edge. No-max softmax. Grouped n2e
// gather: 4 lane-groups x 16 lanes x 16B row slices, unroll-4 (16 j in flight).
__global__ __launch_bounds__(128) void fused_edge_kernel(
    const int* __restrict__ nidx, const int* __restrict__ estart,
    const float* __restrict__ alpha_l, const float* __restrict__ alpha_r,
    const unsigned int* __restrict__ node_feats_bf,
    const unsigned int* __restrict__ edge_feats_bf,
    int* __restrict__ cursor, u32x4* __restrict__ packG,
    unsigned int* __restrict__ edge_aggr_bf)
{
    __shared__ uint4 sInc[2][64];  // wave-private broadcast buffer
    const int e_id = (blockIdx.x * 128 + threadIdx.x) >> 6;
    const int lane = threadIdx.x & 63;
    const int w    = (threadIdx.x >> 6) & 1;
    if (e_id >= NEDGES) return;
    const int s = estart[e_id], t = estart[e_id + 1];
    if (s >= t) return;
    const int deg = t - s;
    const float4 ar = ((const float4*)alpha_r)[e_id];

    // ---- pass A: gather + exp + sum (chunks 0,1 cached in registers)
    int    nc0 = 0, nc1 = 0;
    float4 sc0 = make_float4(0.f, 0.f, 0.f, 0.f), sc1 = sc0;
    float s0 = 0.f, s1 = 0.f, s2 = 0.f, s3 = 0.f;
    if (s + lane < t) {
        nc0 = nidx[s + lane];
        const float4 al = ((const float4*)alpha_l)[nc0];
        sc0.x = __expf(al.x + ar.x); sc0.y = __expf(al.y + ar.y);
        sc0.z = __expf(al.z + ar.z); sc0.w = __expf(al.w + ar.w);
        s0 += sc0.x; s1 += sc0.y; s2 += sc0.z; s3 += sc0.w;
    }
    if (deg > 64 && s + 64 + lane < t) {
        nc1 = nidx[s + 64 + lane];
        const float4 al = ((const float4*)alpha_l)[nc1];
        sc1.x = __expf(al.x + ar.x); sc1.y = __expf(al.y + ar.y);
        sc1.z = __expf(al.z + ar.z); sc1.w = __expf(al.w + ar.w);
        s0 += sc1.x; s1 += sc1.y; s2 += sc1.z; s3 += sc1.w;
    }
    for (int c = 2; c * 64 < deg; ++c) {  // cold path (deg > 128)
        const int i = s + c * 64 + lane;
        if (i < t) {
            const float4 al = ((const float4*)alpha_l)[nidx[i]];
            s0 += __expf(al.x + ar.x); s1 += __expf(al.y + ar.y);
            s2 += __expf(al.z + ar.z); s3 += __expf(al.w + ar.w);
        }
    }
#pragma unroll
    for (int d = 1; d < 64; d <<= 1) {
        s0 += __shfl_xor(s0, d); s1 += __shfl_xor(s1, d);
        s2 += __shfl_xor(s2, d); s3 += __shfl_xor(s3, d);
    }
    const float i0 = 1.f / s0, i1 = 1.f / s1, i2 = 1.f / s2, i3 = 1.f / s3;

    // ---- pass B: publish (n, bf16-alpha) to LDS + packed scatter + grouped
    // n2e gather (unroll-4: 16 incidences, 4 row-gathers in flight).
    const int lg = lane >> 4, ll = lane & 15, hh = ll >> 2;
    float acc[8] = {0.f, 0.f, 0.f, 0.f, 0.f, 0.f, 0.f, 0.f};
    for (int c = 0; c * 64 < deg; ++c) {
        const int i = s + c * 64 + lane;
        int nn = 0;
        float4 a4 = make_float4(0.f, 0.f, 0.f, 0.f);
        if (c == 0) {
            nn = nc0;
            a4 = make_float4(sc0.x * i0, sc0.y * i1, sc0.z * i2, sc0.w * i3);
        } else if (c == 1) {
            nn = nc1;
            a4 = make_float4(sc1.x * i0, sc1.y * i1, sc1.z * i2, sc1.w * i3);
        } else if (i < t) {
            nn = nidx[i];
            const float4 al = ((const float4*)alpha_l)[nn];
            a4.x = __expf(al.x + ar.x) * i0; a4.y = __expf(al.y + ar.y) * i1;
            a4.z = __expf(al.z + ar.z) * i2; a4.w = __expf(al.w + ar.w) * i3;
        }
        const unsigned int a01 = f2bf(a4.x) | (f2bf(a4.y) << 16);
        const unsigned int a23 = f2bf(a4.z) | (f2bf(a4.w) << 16);
        if (i < t) {
            const int pos = atomicAdd(&cursor[nn], 1);
            u32x4 g4;
            g4[0] = (unsigned)e_id; g4[1] = a01; g4[2] = a23; g4[3] = 0u;
            packG[pos] = g4;
        }
        uint4 l4; l4.x = (unsigned)nn; l4.y = a01; l4.z = a23; l4.w = 0u;
        sInc[w][lane] = l4;
        asm volatile("s_waitcnt lgkmcnt(0)" ::: "memory");
        const int mj = min(64, deg - c * 64);
        int jj = 0;
        for (; jj + 16 <= mj; jj += 16) {
            uint4 P[4]; u32x4 V[4]; float Q[4];
#pragma unroll
            for (int u = 0; u < 4; ++u) P[u] = sInc[w][jj + 4 * u + lg];
#pragma unroll
            for (int u = 0; u < 4; ++u)
                V[u] = *(const u32x4*)(node_feats_bf + (size_t)P[u].x * 64 + ll * 4);
#pragma unroll
            for (int u = 0; u < 4; ++u) {
                const unsigned int pr = (hh & 2) ? P[u].z : P[u].y;
                Q[u] = bf2f((hh & 1) ? (pr >> 16) : (pr & 0xffffu));
            }
#pragma unroll
            for (int u = 0; u < 4; ++u)
#pragma unroll
                for (int k = 0; k < 4; ++k) {
                    acc[2 * k]     = fmaf(bf2f(V[u][k] & 0xffffu), Q[u], acc[2 * k]);
                    acc[2 * k + 1] = fmaf(bf2f(V[u][k] >> 16),     Q[u], acc[2 * k + 1]);
                }
        }
        for (; jj + 8 <= mj; jj += 8) {
            const uint4 p1 = sInc[w][jj + lg];
            const uint4 p2 = sInc[w][jj + 4 + lg];
            const u32x4 v1 = *(const u32x4*)(node_feats_bf + (size_t)p1.x * 64 + ll * 4);
            const u32x4 v2 = *(const u32x4*)(node_feats_bf + (size_t)p2.x * 64 + ll * 4);
            const unsigned int pr1 = (hh & 2) ? p1.z : p1.y;
            const unsigned int pr2 = (hh & 2) ? p2.z : p2.y;
            const float q1 = bf2f((hh & 1) ? (pr1 >> 16) : (pr1 & 0xffffu));
            const float q2 = bf2f((hh & 1) ? (pr2 >> 16) : (pr2 & 0xffffu));
#pragma unroll
            for (int k = 0; k < 4; ++k) {
                acc[2 * k]     = fmaf(bf2f(v1[k] & 0xffffu), q1, acc[2 * k]);
                acc[2 * k + 1] = fmaf(bf2f(v1[k] >> 16),     q1, acc[2 * k + 1]);
                acc[2 * k]     = fmaf(bf2f(v2[k] & 0xffffu), q2, acc[2 * k]);
                acc[2 * k + 1] = fmaf(bf2f(v2[k] >> 16),     q2, acc[2 * k + 1]);
            }
        }
        for (; jj < mj; jj += 4) {
            const int j = jj + lg;
            if (j < mj) {
                const uint4 p = sInc[w][j];
                const u32x4 v = *(const u32x4*)(node_feats_bf + (size_t)p.x * 64 + ll * 4);
                const unsigned int pr = (hh & 2) ? p.z : p.y;
                const float q = bf2f((hh & 1) ? (pr >> 16) : (pr & 0xffffu));
#pragma unroll
                for (int k = 0; k < 4; ++k) {
                    acc[2 * k]     = fmaf(bf2f(v[k] & 0xffffu), q, acc[2 * k]);
                    acc[2 * k + 1] = fmaf(bf2f(v[k] >> 16),     q, acc[2 * k + 1]);
                }
            }
        }
    }

    // butterfly-reduce across the 4 groups
#pragma unroll
    for (int k = 0; k < 8; ++k) {
        acc[k] += __shfl_xor(acc[k], 16);
        acc[k] += __shfl_xor(acc[k], 32);
    }
    if (lg == 0) {
        const u32x4 ef = *(const u32x4*)(edge_feats_bf + (size_t)e_id * 64 + ll * 4);
        u32x4 o;
#pragma unroll
        for (int k = 0; k < 4; ++k) {
            const float lo = acc[2 * k]     + bf2f(ef[k] & 0xffffu);
            const float hi = acc[2 * k + 1] + bf2f(ef[k] >> 16);
            o[k] = f2bf(lo) | (f2bf(hi) << 16);
        }
        *(u32x4*)(edge_aggr_bf + (size_t)e_id * 64 + ll * 4) = o;
    }
}

// ---------------------------------------------------------------------------
// K5: edge->node gather, 4-group x 16B-slice structure, butterfly epilogue.
__global__ __launch_bounds__(128) void e2n_gather_kernel(
    const u32x4* __restrict__ packG, const int* __restrict__ node_start,
    const int* __restrict__ cnt, const unsigned int* __restrict__ edge_aggr_bf,
    const float* __restrict__ bias, float* __restrict__ out)
{
    const int n    = (blockIdx.x * 128 + threadIdx.x) >> 6;
    const int lane = threadIdx.x & 63;
    if (n >= NNODES) return;
    const int s   = node_start[n];
    const int deg = cnt[n];
    const int lg = lane >> 4, ll = lane & 15, hh = ll >> 2;
    float acc[8] = {0.f, 0.f, 0.f, 0.f, 0.f, 0.f, 0.f, 0.f};
    int jj = 0;
    for (; jj + 8 <= deg; jj += 8) {
        const u32x4 p1 = packG[s + jj + lg];
        const u32x4 p2 = packG[s + jj + 4 + lg];
        const u32x4 v1 = *(const u32x4*)(edge_aggr_bf + (size_t)p1[0] * 64 + ll * 4);
        const u32x4 v2 = *(const u32x4*)(edge_aggr_bf + (size_t)p2[0] * 64 + ll * 4);
        const unsigned int pr1 = (hh & 2) ? p1[2] : p1[1];
        const unsigned int pr2 = (hh & 2) ? p2[2] : p2[1];
        const float q1 = bf2f((hh & 1) ? (pr1 >> 16) : (pr1 & 0xffffu));
        const float q2 = bf2f((hh & 1) ? (pr2 >> 16) : (pr2 & 0xffffu));
#pragma unroll
        for (int k = 0; k < 4; ++k) {
            acc[2 * k]     = fmaf(bf2f(v1[k] & 0xffffu), q1, acc[2 * k]);
            acc[2 * k + 1] = fmaf(bf2f(v1[k] >> 16),     q1, acc[2 * k + 1]);
            acc[2 * k]     = fmaf(bf2f(v2[k] & 0xffffu), q2, acc[2 * k]);
            acc[2 * k + 1] = fmaf(bf2f(v2[k] >> 16),     q2, acc[2 * k + 1]);
        }
    }
    for (; jj < deg; jj += 4) {
        const int j = jj + lg;
        if (j < deg) {
            const u32x4 p = packG[s + j];
            const u32x4 v = *(const u32x4*)(edge_aggr_bf + (size_t)p[0] * 64 + ll * 4);
            const unsigned int pr = (hh & 2) ? p[2] : p[1];
            const float q = bf2f((hh & 1) ? (pr >> 16) : (pr & 0xffffu));
#pragma unroll
            for (int k = 0; k < 4; ++k) {
                acc[2 * k]     = fmaf(bf2f(v[k] & 0xffffu), q, acc[2 * k]);
                acc[2 * k + 1] = fmaf(bf2f(v[k] >> 16),     q, acc[2 * k + 1]);
            }
        }
    }
#pragma unroll
    for (int k = 0; k < 8; ++k) {
        acc[k] += __shfl_xor(acc[k], 16);
        acc[k] += __shfl_xor(acc[k], 32);
    }
    if (lg < 2) {
        f32x4 o;
#pragma unroll
        for (int k = 0; k < 4; ++k)
            o[k] = acc[4 * lg + k] + bias[8 * ll + 4 * lg + k];
        __builtin_nontemporal_store(o, (f32x4*)(out + (size_t)n * 128 + ll * 8 + lg * 4));
    }
}

// ---------------------------------------------------------------------------
extern "C" void kernel_launch(void* const* d_in, const int* in_sizes, int n_in,
                              void* d_out, int out_size, void* d_ws, size_t ws_size,
                              hipStream_t stream)
{
    const float* x      = (const float*)d_in[0];
    const float* he     = (const float*)d_in[1];
    const int*   nidx   = (const int*)d_in[2];
    const int*   eidx   = (const int*)d_in[3];
    const float* Wn     = (const float*)d_in[4];
    const float* We     = (const float*)d_in[5];
    const float* attn_l = (const float*)d_in[6];
    const float* attn_r = (const float*)d_in[7];
    const float* bias   = (const float*)d_in[8];
    float* out = (float*)d_out;

    char* ws = (char*)d_ws;
    ushort* node_feats = (ushort*)ws;  ws += (size_t)NNODES * 128 * 2;
    ushort* edge_feats = (ushort*)ws;  ws += (size_t)NEDGES * 128 * 2;
    float* alpha_l     = (float*)ws;   ws += (size_t)NNODES * 4 * 4;
    float* alpha_r     = (float*)ws;   ws += (size_t)NEDGES * 4 * 4;
    unsigned int* edge_aggr = (unsigned int*)ws; ws += (size_t)NEDGES * 64 * 4;
    int*   edge_start  = (int*)ws;     ws += (size_t)(NEDGES + 4) * 4;
    int*   cnt         = (int*)ws;     ws += (size_t)(NNODES + 4) * 4;  // +gcursor
    int*   node_start  = (int*)ws;     ws += (size_t)(NNODES + 4) * 4;
    int*   cursor      = (int*)ws;     ws += (size_t)NNODES * 4;
    u32x4* packG       = (u32x4*)ws;   ws += (size_t)NINC * 16;
    ushort* WTn        = (ushort*)ws;  ws += (size_t)128 * 128 * 2;
    ushort* WTe        = (ushort*)ws;  ws += (size_t)128 * 128 * 2;
    int*   gcursor     = cnt + NNODES;

    // prep: edge CSR + zero histogram + W^T (one dispatch)
    prep_kernel<<<CSR_BLKS + 16, 256, 0, stream>>>(eidx, edge_start, cnt, Wn, We, WTn, WTe);
    // histogram (blocks first) + projections (one dispatch; independent work)
    proj_hist_kernel<<<HIST_BLKS + NPROJ, 256, 0, stream>>>(
        x, he, WTn, WTe, attn_l, attn_r, node_feats, edge_feats, alpha_l, alpha_r,
        nidx, cnt);
    assign_kernel<<<(NNODES + 255) / 256, 256, 0, stream>>>(cnt, node_start, cursor, gcursor);
    // fused: softmax (no-max) + packed alpha scatter + grouped n2e aggregation
    fused_edge_kernel<<<(NEDGES * 64 + 127) / 128, 128, 0, stream>>>(
        nidx, edge_start, alpha_l, alpha_r, (const unsigned int*)node_feats,
        (const unsigned int*)edge_feats, cursor, packG, edge_aggr);
    // edge->node gather (grouped)
    e2n_gather_kernel<<<(NNODES * 64 + 127) / 128, 128, 0, stream>>>(
        packG, node_start, cnt, edge_aggr, bias, out);
}